// Round 19
// baseline (756.203 us; speedup 1.0000x reference)
//
#include <hip/hip_runtime.h>
#include <math.h>

#define BATCH 16
#define NPTS 1024
#define KNN 20

__device__ __forceinline__ float lrelu(float v) { return v >= 0.f ? v : 0.2f * v; }

typedef __attribute__((ext_vector_type(8))) short bf16x8;
typedef __attribute__((ext_vector_type(4))) float f32x4;

__device__ __forceinline__ ushort f2bf(float f) {
  union { float f; unsigned u; } v; v.f = f;
  unsigned r = (v.u + 0x7FFFu + ((v.u >> 16) & 1u)) >> 16;  // RNE
  return (ushort)r;
}

// DPP wave-64 min reduction (pure VALU) — verified rounds 10-17.
__device__ __forceinline__ unsigned wave_min_u32(unsigned v) {
  unsigned t;
  t = (unsigned)__builtin_amdgcn_update_dpp((int)v, (int)v, 0x111, 0xf, 0xf, false);
  v = t < v ? t : v;
  t = (unsigned)__builtin_amdgcn_update_dpp((int)v, (int)v, 0x112, 0xf, 0xf, false);
  v = t < v ? t : v;
  t = (unsigned)__builtin_amdgcn_update_dpp((int)v, (int)v, 0x114, 0xf, 0xf, false);
  v = t < v ? t : v;
  t = (unsigned)__builtin_amdgcn_update_dpp((int)v, (int)v, 0x118, 0xf, 0xf, false);
  v = t < v ? t : v;
  t = (unsigned)__builtin_amdgcn_update_dpp((int)v, (int)v, 0x142, 0xf, 0xf, false);
  v = t < v ? t : v;
  t = (unsigned)__builtin_amdgcn_update_dpp((int)v, (int)v, 0x143, 0xf, 0xf, false);
  v = t < v ? t : v;
  return (unsigned)__builtin_amdgcn_readlane((int)v, 63);
}

// ===================================================================
// Dual extraction: 10 rounds, 2 winners/round. Per-lane top-3 kept so
// winner lane's c2 is always its true next candidate. Refill FIX (r19):
// exclude the kept slot from the rebuild; sentinel c1 counts as empty.
// ===================================================================
__device__ __forceinline__ void extract20_dual(const unsigned ku[4][16],
                                               int lane, int wv, long qbase,
                                               int* __restrict__ idxout) {
  const unsigned INVS = 0xFFFFFFFFu;   // empty marker
  const unsigned SENT = 0xFFFFFFFEu;   // exhausted-lane sentinel
  unsigned c1s[4], c2s[4], c3s[4]; int c1j[4], c2j[4], c3j[4];
  #pragma unroll
  for (int r = 0; r < 4; ++r) {
    unsigned b1 = INVS, b2 = INVS, b3 = INVS; int s1 = 0, s2 = 0, s3 = 0;
    #pragma unroll
    for (int s = 0; s < 16; ++s) {
      const unsigned k = ku[r][s];
      const bool a1 = k < b1, a2 = k < b2, a3 = k < b3;
      const unsigned n1 = a1 ? k : b1;             const int t1 = a1 ? s : s1;
      const unsigned n2 = a1 ? b1 : (a2 ? k : b2); const int t2 = a1 ? s1 : (a2 ? s : s2);
      const unsigned n3 = (a1 || a2) ? b2 : (a3 ? k : b3);
      const int t3 = (a1 || a2) ? s2 : (a3 ? s : s3);
      b1 = n1; s1 = t1; b2 = n2; s2 = t2; b3 = n3; s3 = t3;
    }
    c1s[r] = b1; c1j[r] = lane + (s1 << 6);
    c2s[r] = b2; c2j[r] = lane + (s2 << 6);
    c3s[r] = b3; c3j[r] = lane + (s3 << 6);
  }

  int my[4] = {0, 0, 0, 0};
  for (int rd = 0; rd < KNN / 2; ++rd) {
    unsigned m1[4], m2[4]; int wl1[4], wl2[4], jw1[4], jw2[4];
    #pragma unroll
    for (int r = 0; r < 4; ++r) m1[r] = wave_min_u32(c1s[r]);
    #pragma unroll
    for (int r = 0; r < 4; ++r) wl1[r] = __ffsll((long long)__ballot(c1s[r] == m1[r])) - 1;
    unsigned s2v[4]; int j2v[4];
    #pragma unroll
    for (int r = 0; r < 4; ++r) {
      const bool w1 = (lane == wl1[r]);
      s2v[r] = w1 ? c2s[r] : c1s[r];
      j2v[r] = w1 ? c2j[r] : c1j[r];
    }
    #pragma unroll
    for (int r = 0; r < 4; ++r) m2[r] = wave_min_u32(s2v[r]);
    #pragma unroll
    for (int r = 0; r < 4; ++r) wl2[r] = __ffsll((long long)__ballot(s2v[r] == m2[r])) - 1;
    #pragma unroll
    for (int r = 0; r < 4; ++r) jw1[r] = __builtin_amdgcn_readlane(c1j[r], wl1[r]);
    #pragma unroll
    for (int r = 0; r < 4; ++r) jw2[r] = __builtin_amdgcn_readlane(j2v[r], wl2[r]);
    if (lane == 2 * rd) {
      #pragma unroll
      for (int r = 0; r < 4; ++r) my[r] = jw1[r];
    }
    if (lane == 2 * rd + 1) {
      #pragma unroll
      for (int r = 0; r < 4; ++r) my[r] = jw2[r];
    }
    bool needs = false;
    #pragma unroll
    for (int r = 0; r < 4; ++r) {
      const int cons = (int)(lane == wl1[r]) + (int)(lane == wl2[r]);
      const unsigned n1 = (cons == 0) ? c1s[r] : ((cons == 1) ? c2s[r] : c3s[r]);
      const int     o1 = (cons == 0) ? c1j[r] : ((cons == 1) ? c2j[r] : c3j[r]);
      const unsigned n2 = (cons == 0) ? c2s[r] : ((cons == 1) ? c3s[r] : INVS);
      const int     o2 = (cons == 0) ? c2j[r] : ((cons == 1) ? c3j[r] : 0);
      const unsigned n3 = (cons == 0) ? c3s[r] : INVS;
      const int     o3 = (cons == 0) ? c3j[r] : 0;
      c1s[r] = n1; c1j[r] = o1; c2s[r] = n2; c2j[r] = o2; c3s[r] = n3; c3j[r] = o3;
      needs = needs || (c2s[r] == INVS);
    }
    if (__any(needs)) {
      #pragma unroll
      for (int r = 0; r < 4; ++r) {
        if (c2s[r] == INVS) {   // fewer than 2 valid: refill among alive (keys > m2[r])
          const bool haveKeep = (c1s[r] < SENT);
          const int keptslot = (c1j[r] - lane) >> 6;
          unsigned b1 = INVS, b2 = INVS, b3 = INVS; int s1 = 0, s2 = 0, s3 = 0;
          #pragma unroll
          for (int s = 0; s < 16; ++s) {
            const unsigned k = ku[r][s];
            const bool ok = (k > m2[r]) && !(haveKeep && (s == keptslot));
            const bool a1 = ok && (k < b1), a2 = ok && (k < b2), a3 = ok && (k < b3);
            const unsigned n1 = a1 ? k : b1;             const int t1 = a1 ? s : s1;
            const unsigned n2 = a1 ? b1 : (a2 ? k : b2); const int t2 = a1 ? s1 : (a2 ? s : s2);
            const unsigned n3 = (a1 || a2) ? b2 : (a3 ? k : b3);
            const int t3 = (a1 || a2) ? s2 : (a3 ? s : s3);
            b1 = n1; s1 = t1; b2 = n2; s2 = t2; b3 = n3; s3 = t3;
          }
          if (haveKeep) {
            // kept c1 is the smallest alive of this lane; rebuilt list follows it
            c2s[r] = (b1 == INVS) ? SENT : b1;  c2j[r] = lane + (s1 << 6);
            c3s[r] = (b2 == INVS) ? SENT : b2;  c3j[r] = lane + (s2 << 6);
          } else {
            c1s[r] = (b1 == INVS) ? SENT : b1;  c1j[r] = lane + (s1 << 6);
            c2s[r] = (b2 == INVS) ? SENT : b2;  c2j[r] = lane + (s2 << 6);
            c3s[r] = (b3 == INVS) ? SENT : b3;  c3j[r] = lane + (s3 << 6);
          }
        }
      }
    }
  }
  if (lane < KNN) {
    #pragma unroll
    for (int r = 0; r < 4; ++r)
      idxout[(qbase + r * 4 + wv) * KNN + lane] = my[r];
  }
}

// ---- weight-prep work, element-indexed (fused into launch 1 as trailing blocks) ----
struct PrepArgs {
  const float *w2, *w3, *w4, *w5, *tw2, *tw3;
  float *w2aT, *w2dT, *w3aT, *w3dT;
  unsigned short *w4a_bf, *w4d_bf, *w5_bf;
  float *tw2T, *tw3T;
};

__device__ __forceinline__ void prep_elem(int g, const PrepArgs& P) {
  if (g < 524288) { P.w5_bf[g] = f2bf(P.w5[g]); return; }
  g -= 524288;
  if (g < 131072) { int c = g >> 10, o = g & 1023; P.tw3T[g] = P.tw3[o * 128 + c]; return; }
  g -= 131072;
  if (g < 32768) {
    int o = g >> 7, c = g & 127;
    float a = P.w4[o * 256 + c], bb = P.w4[o * 256 + 128 + c];
    P.w4a_bf[g] = f2bf(a); P.w4d_bf[g] = f2bf(bb - a);
    return;
  }
  g -= 32768;
  if (g < 8192) {
    int c = g >> 7, o = g & 127;
    float a = P.w3[o * 128 + c], bb = P.w3[o * 128 + 64 + c];
    P.w3aT[g] = a; P.w3dT[g] = bb - a;
    return;
  }
  g -= 8192;
  if (g < 8192) { int c = g >> 7, o = g & 127; P.tw2T[g] = P.tw2[o * 64 + c]; return; }
  g -= 8192;
  if (g < 4096) {
    int c = g >> 6, o = g & 63;
    float a = P.w2[o * 128 + c], bb = P.w2[o * 128 + 64 + c];
    P.w2aT[g] = a; P.w2dT[g] = bb - a;
  }
}

// ===================================================================
// Fused knn + dual y/z GEMM (+ optional weight-prep trailing blocks).
// ===================================================================
template<int C, int NO, int PREP>
__global__ __launch_bounds__(256)
void knn_dual_kernel(const float* __restrict__ X, long sxb,
                     const float* __restrict__ xx, int* __restrict__ idxout,
                     const float* __restrict__ WaT, const float* __restrict__ WdT,
                     int ldW, float* __restrict__ outY, float* __restrict__ outZ,
                     long sob, int son, PrepArgs P) {
  __shared__ __align__(16) char smem[16384];
  const int gid = blockIdx.x;
  const int tid = threadIdx.x;

  if (PREP && gid >= 1024 + 256 * NO) {
    const int g = (gid - 1024 - 256 * NO) * 256 + tid;
    prep_elem(g, P);
    return;
  }

  if (gid < 1024) {
    // ---------------- knn path ----------------
    float (*sc4)[NPTS] = reinterpret_cast<float (*)[NPTS]>(smem);
    const int b = gid >> 6, i0 = (gid & 63) * 16;
    const float* Xb = X + (size_t)b * sxb;
    const int j0 = tid * 4;
    float acc[16][4];
    #pragma unroll
    for (int q = 0; q < 16; ++q)
      #pragma unroll
      for (int u = 0; u < 4; ++u) acc[q][u] = 0.f;
    float4 xxjv = make_float4(0.f, 0.f, 0.f, 0.f);
    for (int c = 0; c < C; ++c) {
      const float4 xv = *reinterpret_cast<const float4*>(Xb + (size_t)c * NPTS + j0);
      if (C == 3) {
        xxjv.x = fmaf(xv.x, xv.x, xxjv.x);
        xxjv.y = fmaf(xv.y, xv.y, xxjv.y);
        xxjv.z = fmaf(xv.z, xv.z, xxjv.z);
        xxjv.w = fmaf(xv.w, xv.w, xxjv.w);
      }
      const float* xr = Xb + (size_t)c * NPTS + i0;   // uniform -> scalar loads
      #pragma unroll
      for (int q = 0; q < 16; ++q) {
        const float xiq = xr[q];
        acc[q][0] = fmaf(xiq, xv.x, acc[q][0]);
        acc[q][1] = fmaf(xiq, xv.y, acc[q][1]);
        acc[q][2] = fmaf(xiq, xv.z, acc[q][2]);
        acc[q][3] = fmaf(xiq, xv.w, acc[q][3]);
      }
    }
    float4 xxj;
    if (C == 3) xxj = xxjv;
    else xxj = *reinterpret_cast<const float4*>(xx + b * NPTS + j0);
    const int wv = tid >> 6, lane = tid & 63;
    unsigned ku[4][16];

    #pragma unroll
    for (int r = 0; r < 4; ++r) {
      if (r > 0) __syncthreads();
      #pragma unroll
      for (int q = 0; q < 4; ++q) {
        const int qq = r * 4 + q;
        float4 st;
        st.x = fmaf(-2.f, acc[qq][0], xxj.x);
        st.y = fmaf(-2.f, acc[qq][1], xxj.y);
        st.z = fmaf(-2.f, acc[qq][2], xxj.z);
        st.w = fmaf(-2.f, acc[qq][3], xxj.w);
        *reinterpret_cast<float4*>(&sc4[q][j0]) = st;
      }
      __syncthreads();
      #pragma unroll
      for (int s = 0; s < 16; ++s) {
        const unsigned u = __float_as_uint(sc4[wv][lane + 64 * s]);
        ku[r][s] = u ^ ((unsigned)((int)u >> 31) | 0x80000000u);
      }
    }
    extract20_dual(ku, lane, wv, (long)(b * NPTS + i0), idxout);
  } else {
    // ---------------- dual GEMM path (verified body) ----------------
    float (*Xs)[64]  = reinterpret_cast<float (*)[64]>(smem);
    float (*Was)[64] = reinterpret_cast<float (*)[64]>(smem + 4096);
    float (*Wds)[64] = reinterpret_cast<float (*)[64]>(smem + 8192);
    const int g2 = gid - 1024;
    const int bx = g2 & 15;
    const int rest = g2 >> 4;
    const int oy = rest % NO;
    const int b = rest / NO;
    const int n0 = bx * 64, o0 = oy * 64;
    const int lr = tid & 63;
    const int c4 = (tid >> 6) * 4;
    const int tn = tid & 15, to = tid >> 4;
    float accY[4][4], accZ[4][4];
    #pragma unroll
    for (int i = 0; i < 4; ++i)
      #pragma unroll
      for (int j = 0; j < 4; ++j) { accY[i][j] = 0.f; accZ[i][j] = 0.f; }

    const size_t xbase = (size_t)b * sxb;
    for (int k0 = 0; k0 < C; k0 += 16) {
      #pragma unroll
      for (int u = 0; u < 4; ++u) {
        int c = k0 + c4 + u;
        float xv = 0.f, wa = 0.f, wd = 0.f;
        if (c < C) {
          xv = X[xbase + (size_t)(n0 + lr) + (size_t)c * NPTS];
          if (C == 3) {
            const float a = WaT[(size_t)(o0 + lr) * 6 + c];
            wa = a;
            wd = WaT[(size_t)(o0 + lr) * 6 + 3 + c] - a;
          } else {
            wa = WaT[(size_t)c * ldW + o0 + lr];
            wd = WdT[(size_t)c * ldW + o0 + lr];
          }
        }
        Xs[c4 + u][lr] = xv;
        Was[c4 + u][lr] = wa;
        Wds[c4 + u][lr] = wd;
      }
      __syncthreads();
      #pragma unroll
      for (int kk = 0; kk < 16; ++kk) {
        const float4 xa = *reinterpret_cast<const float4*>(&Xs[kk][tn * 4]);
        const float4 wav = *reinterpret_cast<const float4*>(&Was[kk][to * 4]);
        const float4 wdv = *reinterpret_cast<const float4*>(&Wds[kk][to * 4]);
        const float xr[4] = {xa.x, xa.y, xa.z, xa.w};
        const float war[4] = {wav.x, wav.y, wav.z, wav.w};
        const float wdr[4] = {wdv.x, wdv.y, wdv.z, wdv.w};
        #pragma unroll
        for (int i = 0; i < 4; ++i)
          #pragma unroll
          for (int j = 0; j < 4; ++j) {
            accY[i][j] = fmaf(xr[i], war[j], accY[i][j]);
            accZ[i][j] = fmaf(xr[i], wdr[j], accZ[i][j]);
          }
      }
      __syncthreads();
    }
    #pragma unroll
    for (int i = 0; i < 4; ++i) {
      const size_t base = (size_t)b * sob + (size_t)(n0 + tn * 4 + i) * son + o0 + to * 4;
      *reinterpret_cast<float4*>(&outY[base]) =
        make_float4(accY[i][0], accY[i][1], accY[i][2], accY[i][3]);
      *reinterpret_cast<float4*>(&outZ[base]) =
        make_float4(accZ[i][0], accZ[i][1], accZ[i][2], accZ[i][3]);
    }
  }
}

// ===================================================================
// Fused knn<128> + two bf16 MFMA GEMMs (w4a -> ybuf, w4d -> zbuf).
// ===================================================================
__global__ __launch_bounds__(256)
void knn_mfma_kernel(const float* __restrict__ Xt, long sxb,
                     const float* __restrict__ xx, int* __restrict__ idxout,
                     const ushort* __restrict__ Xg,
                     const ushort* __restrict__ w4a, const ushort* __restrict__ w4d,
                     float* __restrict__ ybuf, float* __restrict__ zbuf) {
  __shared__ __align__(16) char smem[32768];
  const int gid = blockIdx.x;
  const int tid = threadIdx.x;

  if (gid < 1024) {
    float (*sc4)[NPTS] = reinterpret_cast<float (*)[NPTS]>(smem);
    const int b = gid >> 6, i0 = (gid & 63) * 16;
    const float* Xb = Xt + (size_t)b * sxb;
    const int j0 = tid * 4;
    float acc[16][4];
    #pragma unroll
    for (int q = 0; q < 16; ++q)
      #pragma unroll
      for (int u = 0; u < 4; ++u) acc[q][u] = 0.f;
    for (int c = 0; c < 128; ++c) {
      const float4 xv = *reinterpret_cast<const float4*>(Xb + (size_t)c * NPTS + j0);
      const float* xr = Xb + (size_t)c * NPTS + i0;
      #pragma unroll
      for (int q = 0; q < 16; ++q) {
        const float xiq = xr[q];
        acc[q][0] = fmaf(xiq, xv.x, acc[q][0]);
        acc[q][1] = fmaf(xiq, xv.y, acc[q][1]);
        acc[q][2] = fmaf(xiq, xv.z, acc[q][2]);
        acc[q][3] = fmaf(xiq, xv.w, acc[q][3]);
      }
    }
    const float4 xxj = *reinterpret_cast<const float4*>(xx + b * NPTS + j0);
    const int wv = tid >> 6, lane = tid & 63;
    unsigned ku[4][16];
    #pragma unroll
    for (int r = 0; r < 4; ++r) {
      if (r > 0) __syncthreads();
      #pragma unroll
      for (int q = 0; q < 4; ++q) {
        const int qq = r * 4 + q;
        float4 st;
        st.x = fmaf(-2.f, acc[qq][0], xxj.x);
        st.y = fmaf(-2.f, acc[qq][1], xxj.y);
        st.z = fmaf(-2.f, acc[qq][2], xxj.z);
        st.w = fmaf(-2.f, acc[qq][3], xxj.w);
        *reinterpret_cast<float4*>(&sc4[q][j0]) = st;
      }
      __syncthreads();
      #pragma unroll
      for (int s = 0; s < 16; ++s) {
        const unsigned u = __float_as_uint(sc4[wv][lane + 64 * s]);
        ku[r][s] = u ^ ((unsigned)((int)u >> 31) | 0x80000000u);
      }
    }
    extract20_dual(ku, lane, wv, (long)(b * NPTS + i0), idxout);
  } else {
    // mfma path (round-7-verified body), K=128, ldX=512, ldW=128
    char* As = smem;
    char* Bs = smem + 16384;
    int g2 = gid - 1024;                    // 0..511
    const ushort* Wg = (g2 < 256) ? w4a : w4d;
    float* outp = (g2 < 256) ? ybuf : zbuf;
    g2 &= 255;
    const int bx = g2 & 7, oy = (g2 >> 3) & 1, b = g2 >> 4;
    const int n0 = bx * 128, o0 = oy * 128;
    const int lane = tid & 63;
    const int wrow = (tid >> 6) >> 1, wcol = (tid >> 6) & 1;
    f32x4 acc[4][4];
    #pragma unroll
    for (int i = 0; i < 4; ++i)
      #pragma unroll
      for (int j = 0; j < 4; ++j)
        #pragma unroll
        for (int r = 0; r < 4; ++r) acc[i][j][r] = 0.f;

    const ushort* Xb = Xg + (size_t)b * NPTS * 512;
    for (int kb = 0; kb < 128; kb += 64) {
      #pragma unroll
      for (int i = 0; i < 4; ++i) {
        const int idx = i * 256 + tid;
        const int n = idx >> 3, kc = idx & 7;
        const bf16x8 xv = *reinterpret_cast<const bf16x8*>(&Xb[(size_t)(n0 + n) * 512 + kb + kc * 8]);
        const bf16x8 wvv = *reinterpret_cast<const bf16x8*>(&Wg[(size_t)(o0 + n) * 128 + kb + kc * 8]);
        const int ad = n * 128 + ((kc * 16) ^ ((n & 7) << 4));
        *reinterpret_cast<bf16x8*>(As + ad) = xv;
        *reinterpret_cast<bf16x8*>(Bs + ad) = wvv;
      }
      __syncthreads();
      #pragma unroll
      for (int s = 0; s < 2; ++s) {
        bf16x8 af[4], bfr[4];
        const int klane = (s * 64 + ((lane >> 4) << 4));
        #pragma unroll
        for (int f = 0; f < 4; ++f) {
          const int nl = wrow * 64 + f * 16 + (lane & 15);
          af[f] = *reinterpret_cast<const bf16x8*>(As + nl * 128 + (klane ^ ((nl & 7) << 4)));
          const int ol = wcol * 64 + f * 16 + (lane & 15);
          bfr[f] = *reinterpret_cast<const bf16x8*>(Bs + ol * 128 + (klane ^ ((ol & 7) << 4)));
        }
        #pragma unroll
        for (int i = 0; i < 4; ++i)
          #pragma unroll
          for (int j = 0; j < 4; ++j)
            acc[i][j] = __builtin_amdgcn_mfma_f32_16x16x32_bf16(af[i], bfr[j], acc[i][j], 0, 0, 0);
      }
      __syncthreads();
    }
    #pragma unroll
    for (int i = 0; i < 4; ++i)
      #pragma unroll
      for (int r = 0; r < 4; ++r) {
        const int n = n0 + wrow * 64 + i * 16 + ((lane >> 4) << 2) + r;
        #pragma unroll
        for (int j = 0; j < 4; ++j) {
          const int o = o0 + wcol * 64 + j * 16 + (lane & 15);
          outp[(size_t)b * NPTS * 256 + (size_t)n * 256 + o] = acc[i][j][r];
        }
      }
  }
}

// ---- 128x128 fp32 GEMM (tw3 path; X channel-major) ----
template<int EPI>
__global__ __launch_bounds__(256)
void gemm128_kernel(const float* __restrict__ X, long sxb, int scN,
                    const float* __restrict__ WT, int ldW, int C,
                    float* __restrict__ out, int sob, int son, int snb) {
  __shared__ __align__(16) float Xs[16][128];
  __shared__ __align__(16) float Ws[16][128];
  __shared__ __align__(16) float red[16][132];
  const int b = blockIdx.z;
  const int n0 = blockIdx.x * 128, o0 = blockIdx.y * 128;
  const int tid = threadIdx.x;
  const int tn = tid & 15, to = tid >> 4;
  float acc[8][8];
  #pragma unroll
  for (int i = 0; i < 8; ++i)
    #pragma unroll
    for (int j = 0; j < 8; ++j) acc[i][j] = 0.f;

  const size_t xbase = (size_t)b * sxb;
  for (int c0 = 0; c0 < C; c0 += 16) {
    #pragma unroll
    for (int it = 0; it < 2; ++it) {
      const int task = tid + it * 256;
      const int kk = task >> 5, n4 = (task & 31) * 4;
      *reinterpret_cast<float4*>(&Xs[kk][n4]) =
        *reinterpret_cast<const float4*>(&X[xbase + (size_t)(c0 + kk) * scN + n0 + n4]);
      *reinterpret_cast<float4*>(&Ws[kk][n4]) =
        *reinterpret_cast<const float4*>(&WT[(size_t)(c0 + kk) * ldW + o0 + n4]);
    }
    __syncthreads();
    #pragma unroll
    for (int kk = 0; kk < 16; ++kk) {
      const float4 xa0 = *reinterpret_cast<const float4*>(&Xs[kk][tn * 4]);
      const float4 xa1 = *reinterpret_cast<const float4*>(&Xs[kk][64 + tn * 4]);
      const float4 wb0 = *reinterpret_cast<const float4*>(&Ws[kk][to * 4]);
      const float4 wb1 = *reinterpret_cast<const float4*>(&Ws[kk][64 + to * 4]);
      const float xr[8] = {xa0.x, xa0.y, xa0.z, xa0.w, xa1.x, xa1.y, xa1.z, xa1.w};
      const float wr[8] = {wb0.x, wb0.y, wb0.z, wb0.w, wb1.x, wb1.y, wb1.z, wb1.w};
      #pragma unroll
      for (int i = 0; i < 8; ++i)
        #pragma unroll
        for (int j = 0; j < 8; ++j) acc[i][j] = fmaf(xr[i], wr[j], acc[i][j]);
    }
    __syncthreads();
  }

  if (EPI == 0) {
    #pragma unroll
    for (int i = 0; i < 8; ++i) {
      const int n = n0 + (i >> 2) * 64 + tn * 4 + (i & 3);
      float4 s0 = make_float4(acc[i][0], acc[i][1], acc[i][2], acc[i][3]);
      float4 s1 = make_float4(acc[i][4], acc[i][5], acc[i][6], acc[i][7]);
      *reinterpret_cast<float4*>(&out[(size_t)b * sob + (size_t)n * son + o0 + to * 4]) = s0;
      *reinterpret_cast<float4*>(&out[(size_t)b * sob + (size_t)n * son + o0 + 64 + to * 4]) = s1;
    }
  } else {
    #pragma unroll
    for (int j = 0; j < 8; ++j) {
      float m = lrelu(acc[0][j]);
      #pragma unroll
      for (int i = 1; i < 8; ++i) m = fmaxf(m, lrelu(acc[i][j]));
      red[tn][(j >> 2) * 64 + to * 4 + (j & 3)] = m;
    }
    __syncthreads();
    if (tid < 128) {
      float m = red[0][tid];
      #pragma unroll
      for (int t = 1; t < 16; ++t) m = fmaxf(m, red[t][tid]);
      out[(size_t)b * sob + (size_t)blockIdx.x * snb + o0 + tid] = m;
    }
  }
}

// ---- bf16 MFMA GEMM (standalone, w5 path) ----
template<int EPI>
__global__ __launch_bounds__(256)
void gemm_mfma_kernel(const ushort* __restrict__ Xg, long sxb, int ldX,
                      const ushort* __restrict__ Wg, int ldW, int K,
                      float* __restrict__ out, long sob, int son, int snb) {
  __shared__ __align__(16) ushort As[128 * 64];
  __shared__ __align__(16) ushort Bs[128 * 64];
  __shared__ float red[2][128];
  const int b = blockIdx.z;
  const int n0 = blockIdx.x * 128, o0 = blockIdx.y * 128;
  const int tid = threadIdx.x;
  const int lane = tid & 63;
  const int wrow = (tid >> 6) >> 1, wcol = (tid >> 6) & 1;
  f32x4 acc[4][4];
  #pragma unroll
  for (int i = 0; i < 4; ++i)
    #pragma unroll
    for (int j = 0; j < 4; ++j)
      #pragma unroll
      for (int r = 0; r < 4; ++r) acc[i][j][r] = 0.f;

  const ushort* Xb = Xg + (size_t)b * sxb;
  for (int kb = 0; kb < K; kb += 64) {
    #pragma unroll
    for (int i = 0; i < 4; ++i) {
      const int idx = i * 256 + tid;
      const int n = idx >> 3, kc = idx & 7;
      const bf16x8 xv = *reinterpret_cast<const bf16x8*>(&Xb[(size_t)(n0 + n) * ldX + kb + kc * 8]);
      const bf16x8 wv = *reinterpret_cast<const bf16x8*>(&Wg[(size_t)(o0 + n) * ldW + kb + kc * 8]);
      const int ad = n * 128 + ((kc * 16) ^ ((n & 7) << 4));
      *reinterpret_cast<bf16x8*>((char*)As + ad) = xv;
      *reinterpret_cast<bf16x8*>((char*)Bs + ad) = wv;
    }
    __syncthreads();
    #pragma unroll
    for (int s = 0; s < 2; ++s) {
      bf16x8 af[4], bfr[4];
      const int klane = (s * 64 + ((lane >> 4) << 4));
      #pragma unroll
      for (int f = 0; f < 4; ++f) {
        const int nl = wrow * 64 + f * 16 + (lane & 15);
        af[f] = *reinterpret_cast<const bf16x8*>((char*)As + nl * 128 + (klane ^ ((nl & 7) << 4)));
        const int ol = wcol * 64 + f * 16 + (lane & 15);
        bfr[f] = *reinterpret_cast<const bf16x8*>((char*)Bs + ol * 128 + (klane ^ ((ol & 7) << 4)));
      }
      #pragma unroll
      for (int i = 0; i < 4; ++i)
        #pragma unroll
        for (int j = 0; j < 4; ++j)
          acc[i][j] = __builtin_amdgcn_mfma_f32_16x16x32_bf16(af[i], bfr[j], acc[i][j], 0, 0, 0);
    }
    __syncthreads();
  }

  if (EPI == 0) {
    #pragma unroll
    for (int i = 0; i < 4; ++i)
      #pragma unroll
      for (int r = 0; r < 4; ++r) {
        const int n = n0 + wrow * 64 + i * 16 + ((lane >> 4) << 2) + r;
        #pragma unroll
        for (int j = 0; j < 4; ++j) {
          const int o = o0 + wcol * 64 + j * 16 + (lane & 15);
          out[(size_t)b * sob + (size_t)n * son + o] = acc[i][j][r];
        }
      }
  } else {
    #pragma unroll
    for (int j = 0; j < 4; ++j) {
      float m = -3.4e38f;
      #pragma unroll
      for (int i = 0; i < 4; ++i)
        #pragma unroll
        for (int r = 0; r < 4; ++r) m = fmaxf(m, lrelu(acc[i][j][r]));
      m = fmaxf(m, __shfl_xor(m, 16));
      m = fmaxf(m, __shfl_xor(m, 32));
      if (lane < 16) red[wrow][wcol * 64 + j * 16 + lane] = m;
    }
    __syncthreads();
    if (tid < 128) {
      float m = fmaxf(red[0][tid], red[1][tid]);
      out[(size_t)b * sob + (size_t)blockIdx.x * snb + o0 + tid] = m;
    }
  }
}

// ---- edge max, channel-major fp32 output + NC bf16 copy ----
template<int O, int TI>
__global__ __launch_bounds__(256)
void edge_max_cn_kernel(const float* __restrict__ y, const float* __restrict__ z,
                        const int* __restrict__ idx, float* __restrict__ outCN,
                        float* __restrict__ xx, ushort* __restrict__ xbf, int choff) {
  __shared__ float tile[TI][O + 1];
  const int b = blockIdx.y;
  const int i0 = blockIdx.x * TI;
  const int wv = threadIdx.x >> 6, lane = threadIdx.x & 63;
  constexpr int OSEG = O / 64;
  constexpr int ROUNDS = TI * OSEG / 4;
  for (int r = 0; r < ROUNDS; ++r) {
    const int item = r * 4 + wv;
    const int il = item / OSEG, os = item - il * OSEG;
    const int i = i0 + il, o = os * 64 + lane;
    const int* ip = idx + (size_t)(b * NPTS + i) * KNN;
    const float zv = z[(size_t)(b * NPTS + i) * O + o];
    float m = -3.4e38f;
    #pragma unroll
    for (int t = 0; t < KNN; ++t) {
      int j = ip[t];
      float v = y[(size_t)(b * NPTS + j) * O + o] + zv;
      m = fmaxf(m, lrelu(v));
    }
    tile[il][o] = m;
    xbf[(size_t)(b * NPTS + i) * 512 + choff + o] = f2bf(m);
  }
  __syncthreads();
  if (xx != nullptr && threadIdx.x < TI) {
    const int il = threadIdx.x;
    float s = 0.f;
    #pragma unroll
    for (int o = 0; o < O; ++o) { float v = tile[il][o]; s = fmaf(v, v, s); }
    xx[b * NPTS + i0 + il] = s;
  }
  for (int e = threadIdx.x; e < TI * O; e += 256) {
    const int o = e / TI, il = e - o * TI;
    outCN[(size_t)b * 512 * NPTS + (size_t)o * NPTS + i0 + il] = tile[il][o];
  }
}

// ---- h12 as edge-GEMM ----
__global__ __launch_bounds__(256)
void h12_gemm_kernel(const float* __restrict__ ya, const float* __restrict__ zb,
                     const int* __restrict__ idx, const float* __restrict__ tw2T,
                     float* __restrict__ h2m) {
  __shared__ __align__(16) float h1s[80][68];
  __shared__ __align__(16) float ws[64][128];
  __shared__ __align__(16) float zbs[4][64];
  __shared__ float ot[128][4];
  __shared__ int idxs[4][KNN];
  const int b = blockIdx.y;
  const int i0 = blockIdx.x * 4;
  const int tid = threadIdx.x;

  #pragma unroll
  for (int it = 0; it < 8; ++it) {
    const int f = tid + it * 256;
    *reinterpret_cast<float4*>(&ws[0][0] + f * 4) =
      *reinterpret_cast<const float4*>(tw2T + (size_t)f * 4);
  }
  if (tid < 64) {
    const int p = tid >> 4, cq = (tid & 15) * 4;
    *reinterpret_cast<float4*>(&zbs[p][cq]) =
      *reinterpret_cast<const float4*>(&zb[(size_t)(b * NPTS + i0 + p) * 64 + cq]);
  }
  if (tid >= 64 && tid < 64 + 4 * KNN) {
    const int e = tid - 64;
    idxs[e / KNN][e % KNN] = idx[(size_t)(b * NPTS + i0) * KNN + e];
  }
  __syncthreads();

  #pragma unroll
  for (int it = 0; it < 5; ++it) {
    const int task = tid + it * 256;
    const int e = task >> 4, cq = (task & 15) * 4;
    const int p = e / KNN, t = e - p * KNN;
    const int j = idxs[p][t];
    const float4 yv = *reinterpret_cast<const float4*>(&ya[(size_t)(b * NPTS + j) * 64 + cq]);
    const float4 zv = *reinterpret_cast<const float4*>(&zbs[p][cq]);
    float4 hv;
    hv.x = lrelu(yv.x + zv.x); hv.y = lrelu(yv.y + zv.y);
    hv.z = lrelu(yv.z + zv.z); hv.w = lrelu(yv.w + zv.w);
    *reinterpret_cast<float4*>(&h1s[e][cq]) = hv;
  }
  __syncthreads();

  const int eg = tid >> 4, og = tid & 15;
  float acc[5][8];
  #pragma unroll
  for (int u = 0; u < 5; ++u)
    #pragma unroll
    for (int v = 0; v < 8; ++v) acc[u][v] = 0.f;
  #pragma unroll 4
  for (int kk = 0; kk < 64; ++kk) {
    float hv[5];
    #pragma unroll
    for (int u = 0; u < 5; ++u) hv[u] = h1s[eg * 5 + u][kk];
    const float4 w0 = *reinterpret_cast<const float4*>(&ws[kk][og * 4]);
    const float4 w1 = *reinterpret_cast<const float4*>(&ws[kk][64 + og * 4]);
    const float wr[8] = {w0.x, w0.y, w0.z, w0.w, w1.x, w1.y, w1.z, w1.w};
    #pragma unroll
    for (int u = 0; u < 5; ++u)
      #pragma unroll
      for (int v = 0; v < 8; ++v) acc[u][v] = fmaf(hv[u], wr[v], acc[u][v]);
  }

  const int p = eg >> 2, d = eg & 3;
  float m[8];
  #pragma unroll
  for (int v = 0; v < 8; ++v) {
    float mm = lrelu(acc[0][v]);
    #pragma unroll
    for (int u = 1; u < 5; ++u) mm = fmaxf(mm, lrelu(acc[u][v]));
    mm = fmaxf(mm, __shfl_xor(mm, 16));
    mm = fmaxf(mm, __shfl_xor(mm, 32));
    m[v] = mm;
  }
  if (d == 0) {
    #pragma unroll
    for (int v = 0; v < 8; ++v) {
      const int o = og * 4 + (v & 3) + (v >> 2) * 64;
      ot[o][p] = m[v];
    }
  }
  __syncthreads();
  if (tid < 128) {
    float4 st = make_float4(ot[tid][0], ot[tid][1], ot[tid][2], ot[tid][3]);
    *reinterpret_cast<float4*>(&h2m[(size_t)(b * 128 + tid) * NPTS + i0]) = st;
  }
}

// ---- reduce partial max over nt n-tiles ----
__global__ __launch_bounds__(256)
void reduce_max_kernel(const float* __restrict__ part, float* __restrict__ outp, int nt) {
  const int b = blockIdx.y;
  const int o = blockIdx.x * 256 + threadIdx.x;
  float m = part[(size_t)(b * nt) * 1024 + o];
  for (int t = 1; t < nt; ++t) m = fmaxf(m, part[(size_t)(b * nt + t) * 1024 + o]);
  outp[b * 1024 + o] = m;
}

// ---- block reduce helper ----
__device__ __forceinline__ float block_reduce_sum(float v, float* rbuf) {
  #pragma unroll
  for (int off = 32; off > 0; off >>= 1) v += __shfl_xor(v, off);
  const int w = threadIdx.x >> 6, lane = threadIdx.x & 63;
  const int nw = blockDim.x >> 6;
  if (lane == 0) rbuf[w] = v;
  __syncthreads();
  float tot = 0.f;
  for (int i = 0; i < nw; ++i) tot += rbuf[i];
  __syncthreads();
  return tot;
}

// ---- fused fc pipeline: max(part)->fc1->fc2->fc3(+I)->xform ----
__global__ __launch_bounds__(256)
void fcall_kernel(const float* __restrict__ part,
                  const float* __restrict__ Wt1, const float* __restrict__ g1,
                  const float* __restrict__ bb1,
                  const float* __restrict__ Wt2, const float* __restrict__ bias2,
                  const float* __restrict__ g2, const float* __restrict__ bb2,
                  const float* __restrict__ Wt3, const float* __restrict__ bb3,
                  const float* __restrict__ x, float* __restrict__ xt) {
  __shared__ __align__(16) float gin[1024];
  __shared__ __align__(16) float f1s[512];
  __shared__ float f2s[256];
  __shared__ float hbuf[512];
  __shared__ float rbuf[8];
  __shared__ float tm[9];
  const int b = blockIdx.x, tid = threadIdx.x;
  for (int e = tid; e < 1024; e += 256) {
    const float* pp = part + (size_t)b * 8192 + e;
    float m = pp[0];
    #pragma unroll
    for (int t = 1; t < 8; ++t) m = fmaxf(m, pp[t * 1024]);
    gin[e] = m;
  }
  __syncthreads();
  float ps = 0.f;
  for (int e = tid; e < 1024; e += 256) ps = fmaf(gin[e], gin[e], ps);
  float ss = block_reduce_sum(ps, rbuf);
  float rinv = 1.0f / sqrtf(ss);
  #pragma unroll
  for (int r = 0; r < 2; ++r) {
    int o = tid + r * 256;
    const float* wrow = Wt1 + (size_t)o * 1024;
    float a = 0.f;
    for (int c4 = 0; c4 < 256; ++c4) {
      float4 wv = *reinterpret_cast<const float4*>(wrow + c4 * 4);
      float4 gv = *reinterpret_cast<const float4*>(&gin[c4 * 4]);
      a = fmaf(wv.x, gv.x, a); a = fmaf(wv.y, gv.y, a);
      a = fmaf(wv.z, gv.z, a); a = fmaf(wv.w, gv.w, a);
    }
    hbuf[o] = a * rinv;
  }
  __syncthreads();
  float pm = hbuf[tid] + hbuf[tid + 256];
  float mean = block_reduce_sum(pm, rbuf) * (1.f / 512.f);
  float d0 = hbuf[tid] - mean, d1 = hbuf[tid + 256] - mean;
  float var = block_reduce_sum(d0 * d0 + d1 * d1, rbuf) * (1.f / 512.f);
  float rs = 1.0f / sqrtf(var + 1e-5f);
  #pragma unroll
  for (int r = 0; r < 2; ++r) {
    int o = tid + r * 256;
    f1s[o] = lrelu((hbuf[o] - mean) * rs * g1[o] + bb1[o]);
  }
  __syncthreads();
  float ps2 = 0.f;
  for (int e = tid; e < 512; e += 256) ps2 = fmaf(f1s[e], f1s[e], ps2);
  float ss2 = block_reduce_sum(ps2, rbuf);
  float rinv2 = 1.0f / sqrtf(ss2);
  const float* wrow2 = Wt2 + (size_t)tid * 512;
  float a2 = 0.f;
  for (int c4 = 0; c4 < 128; ++c4) {
    float4 wv = *reinterpret_cast<const float4*>(wrow2 + c4 * 4);
    float4 gv = *reinterpret_cast<const float4*>(&f1s[c4 * 4]);
    a2 = fmaf(wv.x, gv.x, a2); a2 = fmaf(wv.y, gv.y, a2);
    a2 = fmaf(wv.z, gv.z, a2); a2 = fmaf(wv.w, gv.w, a2);
  }
  a2 = a2 * rinv2 + bias2[tid];
  float mean2 = block_reduce_sum(a2, rbuf) * (1.f / 256.f);
  float dd = a2 - mean2;
  float var2 = block_reduce_sum(dd * dd, rbuf) * (1.f / 256.f);
  float rs2 = 1.0f / sqrtf(var2 + 1e-5f);
  f2s[tid] = lrelu((a2 - mean2) * rs2 * g2[tid] + bb2[tid]);
  __syncthreads();
  if (tid < 9) {
    const float* wrow3 = Wt3 + tid * 256;
    float a3 = 0.f;
    for (int c = 0; c < 256; ++c) a3 = fmaf(wrow3[c], f2s[c], a3);
    a3 += bb3[tid];
    if (tid == 0 || tid == 4 || tid == 8) a3 += 1.f;
    tm[tid] = a3;
  }
  __syncthreads();
  const float* xb = x + (size_t)b * 3 * NPTS;
  float* ob = xt + (size_t)b * 3 * NPTS;
  #pragma unroll
  for (int nt = 0; nt < 4; ++nt) {
    const int n = nt * 256 + tid;
    const float x0 = xb[n], x1 = xb[NPTS + n], x2 = xb[2 * NPTS + n];
    #pragma unroll
    for (int i = 0; i < 3; ++i)
      ob[i * NPTS + n] = fmaf(tm[3 * i], x0, fmaf(tm[3 * i + 1], x1, tm[3 * i + 2] * x2));
  }
}

extern "C" void kernel_launch(void* const* d_in, const int* in_sizes, int n_in,
                              void* d_out, int out_size, void* d_ws, size_t ws_size,
                              hipStream_t stream) {
  (void)in_sizes; (void)n_in; (void)out_size; (void)ws_size;
  const float* x       = (const float*)d_in[0];
  const float* tw1     = (const float*)d_in[1];
  const float* tw2     = (const float*)d_in[2];
  const float* tw3     = (const float*)d_in[3];
  const float* tfc1_w  = (const float*)d_in[4];
  const float* tfc1_g  = (const float*)d_in[5];
  const float* tfc1_b  = (const float*)d_in[6];
  const float* tfc2_w  = (const float*)d_in[7];
  const float* tfc2_bias = (const float*)d_in[8];
  const float* tfc2_g  = (const float*)d_in[9];
  const float* tfc2_b  = (const float*)d_in[10];
  const float* tfc3_w  = (const float*)d_in[11];
  const float* tfc3_b  = (const float*)d_in[12];
  const float* w1      = (const float*)d_in[13];
  const float* w2      = (const float*)d_in[14];
  const float* w3      = (const float*)d_in[15];
  const float* w4      = (const float*)d_in[16];
  const float* w5      = (const float*)d_in[17];
  float* out = (float*)d_out;

  char* wsb = (char*)d_ws;
  size_t off = 0;
  auto alloc = [&](size_t bytes) -> void* {
    void* p = wsb + off;
    off += (bytes + 255) & ~(size_t)255;
    return p;
  };
  float* ybuf = (float*)alloc((size_t)BATCH * NPTS * 256 * 4);
  float* zbuf = (float*)alloc((size_t)BATCH * NPTS * 256 * 4);
  float* xcT  = (float*)alloc((size_t)BATCH * 512 * NPTS * 4);   // channel-major fp32 (knn)
  ushort* xc_bf = (ushort*)alloc((size_t)BATCH * NPTS * 512 * 2); // NC bf16 (MFMA)
  float* h2m  = (float*)alloc((size_t)BATCH * 128 * NPTS * 4);
  float* part = (float*)alloc((size_t)BATCH * 16 * 1024 * 4);
  int*   idxb = (int*)alloc((size_t)BATCH * NPTS * KNN * 4);
  float* xxb  = (float*)alloc((size_t)BATCH * NPTS * 4);
  float* xt   = (float*)alloc((size_t)BATCH * 3 * NPTS * 4);
  float* w2aT  = (float*)alloc(64 * 64 * 4);
  float* w2dT  = (float*)alloc(64 * 64 * 4);
  float* w3aT  = (float*)alloc(64 * 128 * 4);
  float* w3dT  = (float*)alloc(64 * 128 * 4);
  ushort* w4a_bf = (ushort*)alloc(256 * 128 * 2);
  ushort* w4d_bf = (ushort*)alloc(256 * 128 * 2);
  ushort* w5_bf  = (ushort*)alloc(1024 * 512 * 2);
  float* tw2T  = (float*)alloc(64 * 128 * 4);
  float* tw3T  = (float*)alloc(128 * 1024 * 4);

  PrepArgs pa;
  pa.w2 = w2; pa.w3 = w3; pa.w4 = w4; pa.w5 = w5; pa.tw2 = tw2; pa.tw3 = tw3;
  pa.w2aT = w2aT; pa.w2dT = w2dT; pa.w3aT = w3aT; pa.w3dT = w3dT;
  pa.w4a_bf = w4a_bf; pa.w4d_bf = w4d_bf; pa.w5_bf = w5_bf;
  pa.tw2T = tw2T; pa.tw3T = tw3T;
  PrepArgs pnone = {};

  // ---- transform net: fused knn<3> + tw1 dual GEMM (inline split) + ALL weight prep ----
  knn_dual_kernel<3, 1, 1><<<1024 + 256 + 2768, 256, 0, stream>>>(
      x, 3 * NPTS, nullptr, idxb, tw1, tw1, 64,
      ybuf, zbuf, (long)NPTS * 64, 64, pa);
  h12_gemm_kernel<<<dim3(256, 16), 256, 0, stream>>>(ybuf, zbuf, idxb, tw2T, h2m);
  gemm128_kernel<1><<<dim3(8, 8, 16), 256, 0, stream>>>(h2m, 128 * NPTS, NPTS, tw3T, 1024, 128,
                                                        part, 8 * 1024, 0, 1024);
  fcall_kernel<<<16, 256, 0, stream>>>(part, tfc1_w, tfc1_g, tfc1_b,
                                       tfc2_w, tfc2_bias, tfc2_g, tfc2_b,
                                       tfc3_w, tfc3_b, x, xt);

  // ---- EdgeConv 1: fused knn<3> + w1 dual GEMM (inline split) on xt ----
  knn_dual_kernel<3, 1, 0><<<1280, 256, 0, stream>>>(xt, 3 * NPTS, nullptr, idxb,
                                                     w1, w1, 64,
                                                     ybuf, zbuf, (long)NPTS * 64, 64, pnone);
  edge_max_cn_kernel<64, 64><<<dim3(16, 16), 256, 0, stream>>>(ybuf, zbuf, idxb, xcT, xxb,
                                                               xc_bf, 0);

  // ---- EdgeConv 2: fused knn<64> + w2 dual GEMM on xcT ch0-63 ----
  knn_dual_kernel<64, 1, 0><<<1280, 256, 0, stream>>>(xcT, 512 * NPTS, xxb, idxb,
                                                      w2aT, w2dT, 64,
                                                      ybuf, zbuf, (long)NPTS * 64, 64, pnone);
  edge_max_cn_kernel<64, 64><<<dim3(16, 16), 256, 0, stream>>>(ybuf, zbuf, idxb,
                                                               xcT + 64 * NPTS, xxb, xc_bf, 64);

  // ---- EdgeConv 3: fused knn<64> + w3 dual GEMM on xcT ch64-127 ----
  knn_dual_kernel<64, 2, 0><<<1536, 256, 0, stream>>>(xcT + 64 * NPTS, 512 * NPTS, xxb, idxb,
                                                      w3aT, w3dT, 128,
                                                      ybuf, zbuf, (long)NPTS * 128, 128, pnone);
  edge_max_cn_kernel<128, 64><<<dim3(16, 16), 256, 0, stream>>>(ybuf, zbuf, idxb,
                                                                xcT + 128 * NPTS, xxb, xc_bf, 128);

  // ---- EdgeConv 4: fused knn<128> + both w4 bf16 MFMA GEMMs ----
  knn_mfma_kernel<<<1536, 256, 0, stream>>>(xcT + 128 * NPTS, 512 * NPTS, xxb, idxb,
                                            xc_bf + 128, w4a_bf, w4d_bf, ybuf, zbuf);
  edge_max_cn_kernel<256, 32><<<dim3(32, 16), 256, 0, stream>>>(ybuf, zbuf, idxb,
                                                                xcT + 256 * NPTS, nullptr,
                                                                xc_bf, 256);

  // ---- final: x5 = lrelu(w5 @ xc) with max over n — bf16 MFMA ----
  gemm_mfma_kernel<1><<<dim3(8, 8, 16), 256, 0, stream>>>(xc_bf, (long)NPTS * 512, 512,
                                                          w5_bf, 512, 512,
                                                          part, 8 * 1024, 0, 1024);
  reduce_max_kernel<<<dim3(4, 16), 256, 0, stream>>>(part, out, 8);
}

// Round 20
// 684.091 us; speedup vs baseline: 1.1054x; 1.1054x over previous
//
#include <hip/hip_runtime.h>
#include <math.h>

#define BATCH 16
#define NPTS 1024
#define KNN 20

__device__ __forceinline__ float lrelu(float v) { return v >= 0.f ? v : 0.2f * v; }

typedef __attribute__((ext_vector_type(8))) short bf16x8;
typedef __attribute__((ext_vector_type(4))) float f32x4;

__device__ __forceinline__ ushort f2bf(float f) {
  union { float f; unsigned u; } v; v.f = f;
  unsigned r = (v.u + 0x7FFFu + ((v.u >> 16) & 1u)) >> 16;  // RNE
  return (ushort)r;
}

// DPP wave-64 min reduction (pure VALU) — verified rounds 10-17.
__device__ __forceinline__ unsigned wave_min_u32(unsigned v) {
  unsigned t;
  t = (unsigned)__builtin_amdgcn_update_dpp((int)v, (int)v, 0x111, 0xf, 0xf, false);
  v = t < v ? t : v;
  t = (unsigned)__builtin_amdgcn_update_dpp((int)v, (int)v, 0x112, 0xf, 0xf, false);
  v = t < v ? t : v;
  t = (unsigned)__builtin_amdgcn_update_dpp((int)v, (int)v, 0x114, 0xf, 0xf, false);
  v = t < v ? t : v;
  t = (unsigned)__builtin_amdgcn_update_dpp((int)v, (int)v, 0x118, 0xf, 0xf, false);
  v = t < v ? t : v;
  t = (unsigned)__builtin_amdgcn_update_dpp((int)v, (int)v, 0x142, 0xf, 0xf, false);
  v = t < v ? t : v;
  t = (unsigned)__builtin_amdgcn_update_dpp((int)v, (int)v, 0x143, 0xf, 0xf, false);
  v = t < v ? t : v;
  return (unsigned)__builtin_amdgcn_readlane((int)v, 63);
}

// ---- weight-prep work, element-indexed (fused into launch 1 as trailing blocks) ----
struct PrepArgs {
  const float *w2, *w3, *w4, *w5, *tw2, *tw3;
  float *w2aT, *w2dT, *w3aT, *w3dT;
  unsigned short *w4a_bf, *w4d_bf, *w5_bf;
  float *tw2T, *tw3T;
};

__device__ __forceinline__ void prep_elem(int g, const PrepArgs& P) {
  if (g < 524288) { P.w5_bf[g] = f2bf(P.w5[g]); return; }
  g -= 524288;
  if (g < 131072) { int c = g >> 10, o = g & 1023; P.tw3T[g] = P.tw3[o * 128 + c]; return; }
  g -= 131072;
  if (g < 32768) {
    int o = g >> 7, c = g & 127;
    float a = P.w4[o * 256 + c], bb = P.w4[o * 256 + 128 + c];
    P.w4a_bf[g] = f2bf(a); P.w4d_bf[g] = f2bf(bb - a);
    return;
  }
  g -= 32768;
  if (g < 8192) {
    int c = g >> 7, o = g & 127;
    float a = P.w3[o * 128 + c], bb = P.w3[o * 128 + 64 + c];
    P.w3aT[g] = a; P.w3dT[g] = bb - a;
    return;
  }
  g -= 8192;
  if (g < 8192) { int c = g >> 7, o = g & 127; P.tw2T[g] = P.tw2[o * 64 + c]; return; }
  g -= 8192;
  if (g < 4096) {
    int c = g >> 6, o = g & 63;
    float a = P.w2[o * 128 + c], bb = P.w2[o * 128 + 64 + c];
    P.w2aT[g] = a; P.w2dT[g] = bb - a;
  }
}

// ===================================================================
// Fused knn + dual y/z GEMM (+ optional weight-prep trailing blocks).
// Blocks 0..1023: knn (16 queries each);
// blocks 1024..1024+256*NO-1: gemm_dual tiles;
// if PREP: blocks beyond that run prep_elem (256 elems each).
// For C==3 the gemm path reads the ORIGINAL packed weights (WaT = full
// W[o][2C] pointer) with inline split — no prep dependency in-launch.
// ===================================================================
template<int C, int NO, int PREP>
__global__ __launch_bounds__(256)
void knn_dual_kernel(const float* __restrict__ X, long sxb,
                     const float* __restrict__ xx, int* __restrict__ idxout,
                     const float* __restrict__ WaT, const float* __restrict__ WdT,
                     int ldW, float* __restrict__ outY, float* __restrict__ outZ,
                     long sob, int son, PrepArgs P) {
  __shared__ __align__(16) char smem[16384];
  const int gid = blockIdx.x;
  const int tid = threadIdx.x;

  if (PREP && gid >= 1024 + 256 * NO) {
    const int g = (gid - 1024 - 256 * NO) * 256 + tid;
    prep_elem(g, P);
    return;
  }

  if (gid < 1024) {
    // ---------------- knn path (round-13/14/16/17-verified body) ----------------
    float (*sc4)[NPTS] = reinterpret_cast<float (*)[NPTS]>(smem);
    const int b = gid >> 6, i0 = (gid & 63) * 16;
    const float* Xb = X + (size_t)b * sxb;
    const int j0 = tid * 4;
    float acc[16][4];
    #pragma unroll
    for (int q = 0; q < 16; ++q)
      #pragma unroll
      for (int u = 0; u < 4; ++u) acc[q][u] = 0.f;
    float4 xxjv = make_float4(0.f, 0.f, 0.f, 0.f);
    for (int c = 0; c < C; ++c) {
      const float4 xv = *reinterpret_cast<const float4*>(Xb + (size_t)c * NPTS + j0);
      if (C == 3) {
        xxjv.x = fmaf(xv.x, xv.x, xxjv.x);
        xxjv.y = fmaf(xv.y, xv.y, xxjv.y);
        xxjv.z = fmaf(xv.z, xv.z, xxjv.z);
        xxjv.w = fmaf(xv.w, xv.w, xxjv.w);
      }
      const float* xr = Xb + (size_t)c * NPTS + i0;   // uniform -> scalar loads
      #pragma unroll
      for (int q = 0; q < 16; ++q) {
        const float xiq = xr[q];
        acc[q][0] = fmaf(xiq, xv.x, acc[q][0]);
        acc[q][1] = fmaf(xiq, xv.y, acc[q][1]);
        acc[q][2] = fmaf(xiq, xv.z, acc[q][2]);
        acc[q][3] = fmaf(xiq, xv.w, acc[q][3]);
      }
    }
    float4 xxj;
    if (C == 3) xxj = xxjv;
    else xxj = *reinterpret_cast<const float4*>(xx + b * NPTS + j0);
    const int wv = tid >> 6, lane = tid & 63;
    unsigned ku[4][16];

    #pragma unroll
    for (int r = 0; r < 4; ++r) {
      if (r > 0) __syncthreads();
      #pragma unroll
      for (int q = 0; q < 4; ++q) {
        const int qq = r * 4 + q;
        float4 st;
        st.x = fmaf(-2.f, acc[qq][0], xxj.x);
        st.y = fmaf(-2.f, acc[qq][1], xxj.y);
        st.z = fmaf(-2.f, acc[qq][2], xxj.z);
        st.w = fmaf(-2.f, acc[qq][3], xxj.w);
        *reinterpret_cast<float4*>(&sc4[q][j0]) = st;
      }
      __syncthreads();
      #pragma unroll
      for (int s = 0; s < 16; ++s) {
        const unsigned u = __float_as_uint(sc4[wv][lane + 64 * s]);
        ku[r][s] = u ^ ((unsigned)((int)u >> 31) | 0x80000000u);
      }
    }

    unsigned c1s[4], c2s[4]; int c1j[4], c2j[4];
    #pragma unroll
    for (int r = 0; r < 4; ++r) {
      unsigned b1 = 0xFFFFFFFFu, b2 = 0xFFFFFFFFu; int s1 = 0, s2 = 0;
      #pragma unroll
      for (int s = 0; s < 16; ++s) {
        const unsigned k = ku[r][s];
        const bool a1 = k < b1, a2 = k < b2;
        const unsigned n1 = a1 ? k : b1;  const int ns1 = a1 ? s : s1;
        const unsigned n2 = a1 ? b1 : (a2 ? k : b2);
        const int ns2 = a1 ? s1 : (a2 ? s : s2);
        b1 = n1; s1 = ns1; b2 = n2; s2 = ns2;
      }
      c1s[r] = b1; c1j[r] = lane + (s1 << 6);
      c2s[r] = b2; c2j[r] = lane + (s2 << 6);
    }
    const unsigned INVS = 0xFFFFFFFFu;
    int my[4] = {0, 0, 0, 0};
    for (int t = 0; t < KNN; ++t) {
      unsigned ws[4]; int wl[4], jw[4];
      #pragma unroll
      for (int r = 0; r < 4; ++r) ws[r] = wave_min_u32(c1s[r]);
      #pragma unroll
      for (int r = 0; r < 4; ++r) wl[r] = __ffsll((long long)__ballot(c1s[r] == ws[r])) - 1;
      #pragma unroll
      for (int r = 0; r < 4; ++r) jw[r] = __builtin_amdgcn_readlane(c1j[r], wl[r]);
      if (lane == t) {
        #pragma unroll
        for (int r = 0; r < 4; ++r) my[r] = jw[r];
      }
      bool cons = false;
      #pragma unroll
      for (int r = 0; r < 4; ++r) {
        const bool win = (lane == wl[r]);
        c1s[r] = win ? c2s[r] : c1s[r];
        c1j[r] = win ? c2j[r] : c1j[r];
        c2s[r] = win ? INVS : c2s[r];
        cons = cons || (c1s[r] == INVS);
      }
      if (__any(cons)) {
        #pragma unroll
        for (int r = 0; r < 4; ++r) {
          if (c1s[r] == INVS) {   // refill top-2 among keys > ws[r]
            unsigned m1 = INVS, m2 = INVS; int r1 = 0, r2 = 0;
            #pragma unroll
            for (int s = 0; s < 16; ++s) {
              const unsigned k = ku[r][s];
              const bool ok = k > ws[r];
              const bool a1 = ok && (k < m1), a2 = ok && (k < m2);
              const unsigned nm1 = a1 ? k : m1;  const int nr1 = a1 ? s : r1;
              const unsigned nm2 = a1 ? m1 : (a2 ? k : m2);
              const int nr2 = a1 ? r1 : (a2 ? s : r2);
              m1 = nm1; r1 = nr1; m2 = nm2; r2 = nr2;
            }
            c1s[r] = (m1 == INVS) ? 0xFFFFFFFEu : m1;  c1j[r] = lane + (r1 << 6);
            c2s[r] = (m2 == INVS) ? 0xFFFFFFFEu : m2;  c2j[r] = lane + (r2 << 6);
          }
        }
      }
    }
    if (lane < KNN) {
      #pragma unroll
      for (int r = 0; r < 4; ++r)
        idxout[(size_t)(b * NPTS + i0 + r * 4 + wv) * KNN + lane] = my[r];
    }
  } else {
    // ---------------- dual GEMM path (round-11/16-verified body) ----------------
    float (*Xs)[64]  = reinterpret_cast<float (*)[64]>(smem);
    float (*Was)[64] = reinterpret_cast<float (*)[64]>(smem + 4096);
    float (*Wds)[64] = reinterpret_cast<float (*)[64]>(smem + 8192);
    const int g2 = gid - 1024;
    const int bx = g2 & 15;
    const int rest = g2 >> 4;
    const int oy = rest % NO;
    const int b = rest / NO;
    const int n0 = bx * 64, o0 = oy * 64;
    const int lr = tid & 63;
    const int c4 = (tid >> 6) * 4;
    const int tn = tid & 15, to = tid >> 4;
    float accY[4][4], accZ[4][4];
    #pragma unroll
    for (int i = 0; i < 4; ++i)
      #pragma unroll
      for (int j = 0; j < 4; ++j) { accY[i][j] = 0.f; accZ[i][j] = 0.f; }

    const size_t xbase = (size_t)b * sxb;
    for (int k0 = 0; k0 < C; k0 += 16) {
      #pragma unroll
      for (int u = 0; u < 4; ++u) {
        int c = k0 + c4 + u;
        float xv = 0.f, wa = 0.f, wd = 0.f;
        if (c < C) {
          xv = X[xbase + (size_t)(n0 + lr) + (size_t)c * NPTS];
          if (C == 3) {
            // WaT points at the ORIGINAL W[o][2C] (2C=6) weights; inline split
            const float a = WaT[(size_t)(o0 + lr) * 6 + c];
            wa = a;
            wd = WaT[(size_t)(o0 + lr) * 6 + 3 + c] - a;
          } else {
            wa = WaT[(size_t)c * ldW + o0 + lr];
            wd = WdT[(size_t)c * ldW + o0 + lr];
          }
        }
        Xs[c4 + u][lr] = xv;
        Was[c4 + u][lr] = wa;
        Wds[c4 + u][lr] = wd;
      }
      __syncthreads();
      #pragma unroll
      for (int kk = 0; kk < 16; ++kk) {
        const float4 xa = *reinterpret_cast<const float4*>(&Xs[kk][tn * 4]);
        const float4 wav = *reinterpret_cast<const float4*>(&Was[kk][to * 4]);
        const float4 wdv = *reinterpret_cast<const float4*>(&Wds[kk][to * 4]);
        const float xr[4] = {xa.x, xa.y, xa.z, xa.w};
        const float war[4] = {wav.x, wav.y, wav.z, wav.w};
        const float wdr[4] = {wdv.x, wdv.y, wdv.z, wdv.w};
        #pragma unroll
        for (int i = 0; i < 4; ++i)
          #pragma unroll
          for (int j = 0; j < 4; ++j) {
            accY[i][j] = fmaf(xr[i], war[j], accY[i][j]);
            accZ[i][j] = fmaf(xr[i], wdr[j], accZ[i][j]);
          }
      }
      __syncthreads();
    }
    #pragma unroll
    for (int i = 0; i < 4; ++i) {
      const size_t base = (size_t)b * sob + (size_t)(n0 + tn * 4 + i) * son + o0 + to * 4;
      *reinterpret_cast<float4*>(&outY[base]) =
        make_float4(accY[i][0], accY[i][1], accY[i][2], accY[i][3]);
      *reinterpret_cast<float4*>(&outZ[base]) =
        make_float4(accZ[i][0], accZ[i][1], accZ[i][2], accZ[i][3]);
    }
  }
}

// ===================================================================
// Fused knn<128> + two bf16 MFMA GEMMs (w4a -> ybuf, w4d -> zbuf).
// Blocks 0..1023: knn. Blocks 1024..1535: mfma tiles (256 each).
// ===================================================================
__global__ __launch_bounds__(256)
void knn_mfma_kernel(const float* __restrict__ Xt, long sxb,
                     const float* __restrict__ xx, int* __restrict__ idxout,
                     const ushort* __restrict__ Xg,
                     const ushort* __restrict__ w4a, const ushort* __restrict__ w4d,
                     float* __restrict__ ybuf, float* __restrict__ zbuf) {
  __shared__ __align__(16) char smem[32768];
  const int gid = blockIdx.x;
  const int tid = threadIdx.x;

  if (gid < 1024) {
    // knn<128> path (verified body; xx from buffer)
    float (*sc4)[NPTS] = reinterpret_cast<float (*)[NPTS]>(smem);
    const int b = gid >> 6, i0 = (gid & 63) * 16;
    const float* Xb = Xt + (size_t)b * sxb;
    const int j0 = tid * 4;
    float acc[16][4];
    #pragma unroll
    for (int q = 0; q < 16; ++q)
      #pragma unroll
      for (int u = 0; u < 4; ++u) acc[q][u] = 0.f;
    for (int c = 0; c < 128; ++c) {
      const float4 xv = *reinterpret_cast<const float4*>(Xb + (size_t)c * NPTS + j0);
      const float* xr = Xb + (size_t)c * NPTS + i0;
      #pragma unroll
      for (int q = 0; q < 16; ++q) {
        const float xiq = xr[q];
        acc[q][0] = fmaf(xiq, xv.x, acc[q][0]);
        acc[q][1] = fmaf(xiq, xv.y, acc[q][1]);
        acc[q][2] = fmaf(xiq, xv.z, acc[q][2]);
        acc[q][3] = fmaf(xiq, xv.w, acc[q][3]);
      }
    }
    const float4 xxj = *reinterpret_cast<const float4*>(xx + b * NPTS + j0);
    const int wv = tid >> 6, lane = tid & 63;
    unsigned ku[4][16];
    #pragma unroll
    for (int r = 0; r < 4; ++r) {
      if (r > 0) __syncthreads();
      #pragma unroll
      for (int q = 0; q < 4; ++q) {
        const int qq = r * 4 + q;
        float4 st;
        st.x = fmaf(-2.f, acc[qq][0], xxj.x);
        st.y = fmaf(-2.f, acc[qq][1], xxj.y);
        st.z = fmaf(-2.f, acc[qq][2], xxj.z);
        st.w = fmaf(-2.f, acc[qq][3], xxj.w);
        *reinterpret_cast<float4*>(&sc4[q][j0]) = st;
      }
      __syncthreads();
      #pragma unroll
      for (int s = 0; s < 16; ++s) {
        const unsigned u = __float_as_uint(sc4[wv][lane + 64 * s]);
        ku[r][s] = u ^ ((unsigned)((int)u >> 31) | 0x80000000u);
      }
    }
    unsigned c1s[4], c2s[4]; int c1j[4], c2j[4];
    #pragma unroll
    for (int r = 0; r < 4; ++r) {
      unsigned b1 = 0xFFFFFFFFu, b2 = 0xFFFFFFFFu; int s1 = 0, s2 = 0;
      #pragma unroll
      for (int s = 0; s < 16; ++s) {
        const unsigned k = ku[r][s];
        const bool a1 = k < b1, a2 = k < b2;
        const unsigned n1 = a1 ? k : b1;  const int ns1 = a1 ? s : s1;
        const unsigned n2 = a1 ? b1 : (a2 ? k : b2);
        const int ns2 = a1 ? s1 : (a2 ? s : s2);
        b1 = n1; s1 = ns1; b2 = n2; s2 = ns2;
      }
      c1s[r] = b1; c1j[r] = lane + (s1 << 6);
      c2s[r] = b2; c2j[r] = lane + (s2 << 6);
    }
    const unsigned INVS = 0xFFFFFFFFu;
    int my[4] = {0, 0, 0, 0};
    for (int t = 0; t < KNN; ++t) {
      unsigned ws[4]; int wl[4], jw[4];
      #pragma unroll
      for (int r = 0; r < 4; ++r) ws[r] = wave_min_u32(c1s[r]);
      #pragma unroll
      for (int r = 0; r < 4; ++r) wl[r] = __ffsll((long long)__ballot(c1s[r] == ws[r])) - 1;
      #pragma unroll
      for (int r = 0; r < 4; ++r) jw[r] = __builtin_amdgcn_readlane(c1j[r], wl[r]);
      if (lane == t) {
        #pragma unroll
        for (int r = 0; r < 4; ++r) my[r] = jw[r];
      }
      bool cons = false;
      #pragma unroll
      for (int r = 0; r < 4; ++r) {
        const bool win = (lane == wl[r]);
        c1s[r] = win ? c2s[r] : c1s[r];
        c1j[r] = win ? c2j[r] : c1j[r];
        c2s[r] = win ? INVS : c2s[r];
        cons = cons || (c1s[r] == INVS);
      }
      if (__any(cons)) {
        #pragma unroll
        for (int r = 0; r < 4; ++r) {
          if (c1s[r] == INVS) {
            unsigned m1 = INVS, m2 = INVS; int r1 = 0, r2 = 0;
            #pragma unroll
            for (int s = 0; s < 16; ++s) {
              const unsigned k = ku[r][s];
              const bool ok = k > ws[r];
              const bool a1 = ok && (k < m1), a2 = ok && (k < m2);
              const unsigned nm1 = a1 ? k : m1;  const int nr1 = a1 ? s : r1;
              const unsigned nm2 = a1 ? m1 : (a2 ? k : m2);
              const int nr2 = a1 ? r1 : (a2 ? s : r2);
              m1 = nm1; r1 = nr1; m2 = nm2; r2 = nr2;
            }
            c1s[r] = (m1 == INVS) ? 0xFFFFFFFEu : m1;  c1j[r] = lane + (r1 << 6);
            c2s[r] = (m2 == INVS) ? 0xFFFFFFFEu : m2;  c2j[r] = lane + (r2 << 6);
          }
        }
      }
    }
    if (lane < KNN) {
      #pragma unroll
      for (int r = 0; r < 4; ++r)
        idxout[(size_t)(b * NPTS + i0 + r * 4 + wv) * KNN + lane] = my[r];
    }
  } else {
    // mfma path (round-7-verified body), K=128, ldX=512, ldW=128
    char* As = smem;
    char* Bs = smem + 16384;
    int g2 = gid - 1024;                    // 0..511
    const ushort* Wg = (g2 < 256) ? w4a : w4d;
    float* outp = (g2 < 256) ? ybuf : zbuf;
    g2 &= 255;
    const int bx = g2 & 7, oy = (g2 >> 3) & 1, b = g2 >> 4;
    const int n0 = bx * 128, o0 = oy * 128;
    const int lane = tid & 63;
    const int wrow = (tid >> 6) >> 1, wcol = (tid >> 6) & 1;
    f32x4 acc[4][4];
    #pragma unroll
    for (int i = 0; i < 4; ++i)
      #pragma unroll
      for (int j = 0; j < 4; ++j)
        #pragma unroll
        for (int r = 0; r < 4; ++r) acc[i][j][r] = 0.f;

    const ushort* Xb = Xg + (size_t)b * NPTS * 512;
    for (int kb = 0; kb < 128; kb += 64) {
      #pragma unroll
      for (int i = 0; i < 4; ++i) {
        const int idx = i * 256 + tid;
        const int n = idx >> 3, kc = idx & 7;
        const bf16x8 xv = *reinterpret_cast<const bf16x8*>(&Xb[(size_t)(n0 + n) * 512 + kb + kc * 8]);
        const bf16x8 wvv = *reinterpret_cast<const bf16x8*>(&Wg[(size_t)(o0 + n) * 128 + kb + kc * 8]);
        const int ad = n * 128 + ((kc * 16) ^ ((n & 7) << 4));
        *reinterpret_cast<bf16x8*>(As + ad) = xv;
        *reinterpret_cast<bf16x8*>(Bs + ad) = wvv;
      }
      __syncthreads();
      #pragma unroll
      for (int s = 0; s < 2; ++s) {
        bf16x8 af[4], bfr[4];
        const int klane = (s * 64 + ((lane >> 4) << 4));
        #pragma unroll
        for (int f = 0; f < 4; ++f) {
          const int nl = wrow * 64 + f * 16 + (lane & 15);
          af[f] = *reinterpret_cast<const bf16x8*>(As + nl * 128 + (klane ^ ((nl & 7) << 4)));
          const int ol = wcol * 64 + f * 16 + (lane & 15);
          bfr[f] = *reinterpret_cast<const bf16x8*>(Bs + ol * 128 + (klane ^ ((ol & 7) << 4)));
        }
        #pragma unroll
        for (int i = 0; i < 4; ++i)
          #pragma unroll
          for (int j = 0; j < 4; ++j)
            acc[i][j] = __builtin_amdgcn_mfma_f32_16x16x32_bf16(af[i], bfr[j], acc[i][j], 0, 0, 0);
      }
      __syncthreads();
    }
    #pragma unroll
    for (int i = 0; i < 4; ++i)
      #pragma unroll
      for (int r = 0; r < 4; ++r) {
        const int n = n0 + wrow * 64 + i * 16 + ((lane >> 4) << 2) + r;
        #pragma unroll
        for (int j = 0; j < 4; ++j) {
          const int o = o0 + wcol * 64 + j * 16 + (lane & 15);
          outp[(size_t)b * NPTS * 256 + (size_t)n * 256 + o] = acc[i][j][r];
        }
      }
  }
}

// ---- 128x128 fp32 GEMM (tw3 path; X channel-major) ----
template<int EPI>
__global__ __launch_bounds__(256)
void gemm128_kernel(const float* __restrict__ X, long sxb, int scN,
                    const float* __restrict__ WT, int ldW, int C,
                    float* __restrict__ out, int sob, int son, int snb) {
  __shared__ __align__(16) float Xs[16][128];
  __shared__ __align__(16) float Ws[16][128];
  __shared__ __align__(16) float red[16][132];
  const int b = blockIdx.z;
  const int n0 = blockIdx.x * 128, o0 = blockIdx.y * 128;
  const int tid = threadIdx.x;
  const int tn = tid & 15, to = tid >> 4;
  float acc[8][8];
  #pragma unroll
  for (int i = 0; i < 8; ++i)
    #pragma unroll
    for (int j = 0; j < 8; ++j) acc[i][j] = 0.f;

  const size_t xbase = (size_t)b * sxb;
  for (int c0 = 0; c0 < C; c0 += 16) {
    #pragma unroll
    for (int it = 0; it < 2; ++it) {
      const int task = tid + it * 256;
      const int kk = task >> 5, n4 = (task & 31) * 4;
      *reinterpret_cast<float4*>(&Xs[kk][n4]) =
        *reinterpret_cast<const float4*>(&X[xbase + (size_t)(c0 + kk) * scN + n0 + n4]);
      *reinterpret_cast<float4*>(&Ws[kk][n4]) =
        *reinterpret_cast<const float4*>(&WT[(size_t)(c0 + kk) * ldW + o0 + n4]);
    }
    __syncthreads();
    #pragma unroll
    for (int kk = 0; kk < 16; ++kk) {
      const float4 xa0 = *reinterpret_cast<const float4*>(&Xs[kk][tn * 4]);
      const float4 xa1 = *reinterpret_cast<const float4*>(&Xs[kk][64 + tn * 4]);
      const float4 wb0 = *reinterpret_cast<const float4*>(&Ws[kk][to * 4]);
      const float4 wb1 = *reinterpret_cast<const float4*>(&Ws[kk][64 + to * 4]);
      const float xr[8] = {xa0.x, xa0.y, xa0.z, xa0.w, xa1.x, xa1.y, xa1.z, xa1.w};
      const float wr[8] = {wb0.x, wb0.y, wb0.z, wb0.w, wb1.x, wb1.y, wb1.z, wb1.w};
      #pragma unroll
      for (int i = 0; i < 8; ++i)
        #pragma unroll
        for (int j = 0; j < 8; ++j) acc[i][j] = fmaf(xr[i], wr[j], acc[i][j]);
    }
    __syncthreads();
  }

  if (EPI == 0) {
    #pragma unroll
    for (int i = 0; i < 8; ++i) {
      const int n = n0 + (i >> 2) * 64 + tn * 4 + (i & 3);
      float4 s0 = make_float4(acc[i][0], acc[i][1], acc[i][2], acc[i][3]);
      float4 s1 = make_float4(acc[i][4], acc[i][5], acc[i][6], acc[i][7]);
      *reinterpret_cast<float4*>(&out[(size_t)b * sob + (size_t)n * son + o0 + to * 4]) = s0;
      *reinterpret_cast<float4*>(&out[(size_t)b * sob + (size_t)n * son + o0 + 64 + to * 4]) = s1;
    }
  } else {
    #pragma unroll
    for (int j = 0; j < 8; ++j) {
      float m = lrelu(acc[0][j]);
      #pragma unroll
      for (int i = 1; i < 8; ++i) m = fmaxf(m, lrelu(acc[i][j]));
      red[tn][(j >> 2) * 64 + to * 4 + (j & 3)] = m;
    }
    __syncthreads();
    if (tid < 128) {
      float m = red[0][tid];
      #pragma unroll
      for (int t = 1; t < 16; ++t) m = fmaxf(m, red[t][tid]);
      out[(size_t)b * sob + (size_t)blockIdx.x * snb + o0 + tid] = m;
    }
  }
}

// ---- bf16 MFMA GEMM (standalone, w5 path) ----
template<int EPI>
__global__ __launch_bounds__(256)
void gemm_mfma_kernel(const ushort* __restrict__ Xg, long sxb, int ldX,
                      const ushort* __restrict__ Wg, int ldW, int K,
                      float* __restrict__ out, long sob, int son, int snb) {
  __shared__ __align__(16) ushort As[128 * 64];
  __shared__ __align__(16) ushort Bs[128 * 64];
  __shared__ float red[2][128];
  const int b = blockIdx.z;
  const int n0 = blockIdx.x * 128, o0 = blockIdx.y * 128;
  const int tid = threadIdx.x;
  const int lane = tid & 63;
  const int wrow = (tid >> 6) >> 1, wcol = (tid >> 6) & 1;
  f32x4 acc[4][4];
  #pragma unroll
  for (int i = 0; i < 4; ++i)
    #pragma unroll
    for (int j = 0; j < 4; ++j)
      #pragma unroll
      for (int r = 0; r < 4; ++r) acc[i][j][r] = 0.f;

  const ushort* Xb = Xg + (size_t)b * sxb;
  for (int kb = 0; kb < K; kb += 64) {
    #pragma unroll
    for (int i = 0; i < 4; ++i) {
      const int idx = i * 256 + tid;
      const int n = idx >> 3, kc = idx & 7;
      const bf16x8 xv = *reinterpret_cast<const bf16x8*>(&Xb[(size_t)(n0 + n) * ldX + kb + kc * 8]);
      const bf16x8 wv = *reinterpret_cast<const bf16x8*>(&Wg[(size_t)(o0 + n) * ldW + kb + kc * 8]);
      const int ad = n * 128 + ((kc * 16) ^ ((n & 7) << 4));
      *reinterpret_cast<bf16x8*>((char*)As + ad) = xv;
      *reinterpret_cast<bf16x8*>((char*)Bs + ad) = wv;
    }
    __syncthreads();
    #pragma unroll
    for (int s = 0; s < 2; ++s) {
      bf16x8 af[4], bfr[4];
      const int klane = (s * 64 + ((lane >> 4) << 4));
      #pragma unroll
      for (int f = 0; f < 4; ++f) {
        const int nl = wrow * 64 + f * 16 + (lane & 15);
        af[f] = *reinterpret_cast<const bf16x8*>((char*)As + nl * 128 + (klane ^ ((nl & 7) << 4)));
        const int ol = wcol * 64 + f * 16 + (lane & 15);
        bfr[f] = *reinterpret_cast<const bf16x8*>((char*)Bs + ol * 128 + (klane ^ ((ol & 7) << 4)));
      }
      #pragma unroll
      for (int i = 0; i < 4; ++i)
        #pragma unroll
        for (int j = 0; j < 4; ++j)
          acc[i][j] = __builtin_amdgcn_mfma_f32_16x16x32_bf16(af[i], bfr[j], acc[i][j], 0, 0, 0);
    }
    __syncthreads();
  }

  if (EPI == 0) {
    #pragma unroll
    for (int i = 0; i < 4; ++i)
      #pragma unroll
      for (int r = 0; r < 4; ++r) {
        const int n = n0 + wrow * 64 + i * 16 + ((lane >> 4) << 2) + r;
        #pragma unroll
        for (int j = 0; j < 4; ++j) {
          const int o = o0 + wcol * 64 + j * 16 + (lane & 15);
          out[(size_t)b * sob + (size_t)n * son + o] = acc[i][j][r];
        }
      }
  } else {
    #pragma unroll
    for (int j = 0; j < 4; ++j) {
      float m = -3.4e38f;
      #pragma unroll
      for (int i = 0; i < 4; ++i)
        #pragma unroll
        for (int r = 0; r < 4; ++r) m = fmaxf(m, lrelu(acc[i][j][r]));
      m = fmaxf(m, __shfl_xor(m, 16));
      m = fmaxf(m, __shfl_xor(m, 32));
      if (lane < 16) red[wrow][wcol * 64 + j * 16 + lane] = m;
    }
    __syncthreads();
    if (tid < 128) {
      float m = fmaxf(red[0][tid], red[1][tid]);
      out[(size_t)b * sob + (size_t)blockIdx.x * snb + o0 + tid] = m;
    }
  }
}

// ---- edge max, channel-major fp32 output + NC bf16 copy ----
template<int O, int TI>
__global__ __launch_bounds__(256)
void edge_max_cn_kernel(const float* __restrict__ y, const float* __restrict__ z,
                        const int* __restrict__ idx, float* __restrict__ outCN,
                        float* __restrict__ xx, ushort* __restrict__ xbf, int choff) {
  __shared__ float tile[TI][O + 1];
  const int b = blockIdx.y;
  const int i0 = blockIdx.x * TI;
  const int wv = threadIdx.x >> 6, lane = threadIdx.x & 63;
  constexpr int OSEG = O / 64;
  constexpr int ROUNDS = TI * OSEG / 4;
  for (int r = 0; r < ROUNDS; ++r) {
    const int item = r * 4 + wv;
    const int il = item / OSEG, os = item - il * OSEG;
    const int i = i0 + il, o = os * 64 + lane;
    const int* ip = idx + (size_t)(b * NPTS + i) * KNN;
    const float zv = z[(size_t)(b * NPTS + i) * O + o];
    float m = -3.4e38f;
    #pragma unroll
    for (int t = 0; t < KNN; ++t) {
      int j = ip[t];
      float v = y[(size_t)(b * NPTS + j) * O + o] + zv;
      m = fmaxf(m, lrelu(v));
    }
    tile[il][o] = m;
    xbf[(size_t)(b * NPTS + i) * 512 + choff + o] = f2bf(m);
  }
  __syncthreads();
  if (xx != nullptr && threadIdx.x < TI) {
    const int il = threadIdx.x;
    float s = 0.f;
    #pragma unroll
    for (int o = 0; o < O; ++o) { float v = tile[il][o]; s = fmaf(v, v, s); }
    xx[b * NPTS + i0 + il] = s;
  }
  for (int e = threadIdx.x; e < TI * O; e += 256) {
    const int o = e / TI, il = e - o * TI;
    outCN[(size_t)b * 512 * NPTS + (size_t)o * NPTS + i0 + il] = tile[il][o];
  }
}

// ---- h12 as edge-GEMM ----
__global__ __launch_bounds__(256)
void h12_gemm_kernel(const float* __restrict__ ya, const float* __restrict__ zb,
                     const int* __restrict__ idx, const float* __restrict__ tw2T,
                     float* __restrict__ h2m) {
  __shared__ __align__(16) float h1s[80][68];
  __shared__ __align__(16) float ws[64][128];
  __shared__ __align__(16) float zbs[4][64];
  __shared__ float ot[128][4];
  __shared__ int idxs[4][KNN];
  const int b = blockIdx.y;
  const int i0 = blockIdx.x * 4;
  const int tid = threadIdx.x;

  #pragma unroll
  for (int it = 0; it < 8; ++it) {
    const int f = tid + it * 256;
    *reinterpret_cast<float4*>(&ws[0][0] + f * 4) =
      *reinterpret_cast<const float4*>(tw2T + (size_t)f * 4);
  }
  if (tid < 64) {
    const int p = tid >> 4, cq = (tid & 15) * 4;
    *reinterpret_cast<float4*>(&zbs[p][cq]) =
      *reinterpret_cast<const float4*>(&zb[(size_t)(b * NPTS + i0 + p) * 64 + cq]);
  }
  if (tid >= 64 && tid < 64 + 4 * KNN) {
    const int e = tid - 64;
    idxs[e / KNN][e % KNN] = idx[(size_t)(b * NPTS + i0) * KNN + e];
  }
  __syncthreads();

  #pragma unroll
  for (int it = 0; it < 5; ++it) {
    const int task = tid + it * 256;
    const int e = task >> 4, cq = (task & 15) * 4;
    const int p = e / KNN, t = e - p * KNN;
    const int j = idxs[p][t];
    const float4 yv = *reinterpret_cast<const float4*>(&ya[(size_t)(b * NPTS + j) * 64 + cq]);
    const float4 zv = *reinterpret_cast<const float4*>(&zbs[p][cq]);
    float4 hv;
    hv.x = lrelu(yv.x + zv.x); hv.y = lrelu(yv.y + zv.y);
    hv.z = lrelu(yv.z + zv.z); hv.w = lrelu(yv.w + zv.w);
    *reinterpret_cast<float4*>(&h1s[e][cq]) = hv;
  }
  __syncthreads();

  const int eg = tid >> 4, og = tid & 15;
  float acc[5][8];
  #pragma unroll
  for (int u = 0; u < 5; ++u)
    #pragma unroll
    for (int v = 0; v < 8; ++v) acc[u][v] = 0.f;
  #pragma unroll 4
  for (int kk = 0; kk < 64; ++kk) {
    float hv[5];
    #pragma unroll
    for (int u = 0; u < 5; ++u) hv[u] = h1s[eg * 5 + u][kk];
    const float4 w0 = *reinterpret_cast<const float4*>(&ws[kk][og * 4]);
    const float4 w1 = *reinterpret_cast<const float4*>(&ws[kk][64 + og * 4]);
    const float wr[8] = {w0.x, w0.y, w0.z, w0.w, w1.x, w1.y, w1.z, w1.w};
    #pragma unroll
    for (int u = 0; u < 5; ++u)
      #pragma unroll
      for (int v = 0; v < 8; ++v) acc[u][v] = fmaf(hv[u], wr[v], acc[u][v]);
  }

  const int p = eg >> 2, d = eg & 3;
  float m[8];
  #pragma unroll
  for (int v = 0; v < 8; ++v) {
    float mm = lrelu(acc[0][v]);
    #pragma unroll
    for (int u = 1; u < 5; ++u) mm = fmaxf(mm, lrelu(acc[u][v]));
    mm = fmaxf(mm, __shfl_xor(mm, 16));
    mm = fmaxf(mm, __shfl_xor(mm, 32));
    m[v] = mm;
  }
  if (d == 0) {
    #pragma unroll
    for (int v = 0; v < 8; ++v) {
      const int o = og * 4 + (v & 3) + (v >> 2) * 64;
      ot[o][p] = m[v];
    }
  }
  __syncthreads();
  if (tid < 128) {
    float4 st = make_float4(ot[tid][0], ot[tid][1], ot[tid][2], ot[tid][3]);
    *reinterpret_cast<float4*>(&h2m[(size_t)(b * 128 + tid) * NPTS + i0]) = st;
  }
}

// ---- reduce partial max over nt n-tiles ----
__global__ __launch_bounds__(256)
void reduce_max_kernel(const float* __restrict__ part, float* __restrict__ outp, int nt) {
  const int b = blockIdx.y;
  const int o = blockIdx.x * 256 + threadIdx.x;
  float m = part[(size_t)(b * nt) * 1024 + o];
  for (int t = 1; t < nt; ++t) m = fmaxf(m, part[(size_t)(b * nt + t) * 1024 + o]);
  outp[b * 1024 + o] = m;
}

// ---- block reduce helper ----
__device__ __forceinline__ float block_reduce_sum(float v, float* rbuf) {
  #pragma unroll
  for (int off = 32; off > 0; off >>= 1) v += __shfl_xor(v, off);
  const int w = threadIdx.x >> 6, lane = threadIdx.x & 63;
  const int nw = blockDim.x >> 6;
  if (lane == 0) rbuf[w] = v;
  __syncthreads();
  float tot = 0.f;
  for (int i = 0; i < nw; ++i) tot += rbuf[i];
  __syncthreads();
  return tot;
}

// ---- fused fc pipeline: max(part)->fc1->fc2->fc3(+I)->xform ----
__global__ __launch_bounds__(256)
void fcall_kernel(const float* __restrict__ part,
                  const float* __restrict__ Wt1, const float* __restrict__ g1,
                  const float* __restrict__ bb1,
                  const float* __restrict__ Wt2, const float* __restrict__ bias2,
                  const float* __restrict__ g2, const float* __restrict__ bb2,
                  const float* __restrict__ Wt3, const float* __restrict__ bb3,
                  const float* __restrict__ x, float* __restrict__ xt) {
  __shared__ __align__(16) float gin[1024];
  __shared__ __align__(16) float f1s[512];
  __shared__ float f2s[256];
  __shared__ float hbuf[512];
  __shared__ float rbuf[8];
  __shared__ float tm[9];
  const int b = blockIdx.x, tid = threadIdx.x;
  for (int e = tid; e < 1024; e += 256) {
    const float* pp = part + (size_t)b * 8192 + e;
    float m = pp[0];
    #pragma unroll
    for (int t = 1; t < 8; ++t) m = fmaxf(m, pp[t * 1024]);
    gin[e] = m;
  }
  __syncthreads();
  float ps = 0.f;
  for (int e = tid; e < 1024; e += 256) ps = fmaf(gin[e], gin[e], ps);
  float ss = block_reduce_sum(ps, rbuf);
  float rinv = 1.0f / sqrtf(ss);
  #pragma unroll
  for (int r = 0; r < 2; ++r) {
    int o = tid + r * 256;
    const float* wrow = Wt1 + (size_t)o * 1024;
    float a = 0.f;
    for (int c4 = 0; c4 < 256; ++c4) {
      float4 wv = *reinterpret_cast<const float4*>(wrow + c4 * 4);
      float4 gv = *reinterpret_cast<const float4*>(&gin[c4 * 4]);
      a = fmaf(wv.x, gv.x, a); a = fmaf(wv.y, gv.y, a);
      a = fmaf(wv.z, gv.z, a); a = fmaf(wv.w, gv.w, a);
    }
    hbuf[o] = a * rinv;
  }
  __syncthreads();
  float pm = hbuf[tid] + hbuf[tid + 256];
  float mean = block_reduce_sum(pm, rbuf) * (1.f / 512.f);
  float d0 = hbuf[tid] - mean, d1 = hbuf[tid + 256] - mean;
  float var = block_reduce_sum(d0 * d0 + d1 * d1, rbuf) * (1.f / 512.f);
  float rs = 1.0f / sqrtf(var + 1e-5f);
  #pragma unroll
  for (int r = 0; r < 2; ++r) {
    int o = tid + r * 256;
    f1s[o] = lrelu((hbuf[o] - mean) * rs * g1[o] + bb1[o]);
  }
  __syncthreads();
  float ps2 = 0.f;
  for (int e = tid; e < 512; e += 256) ps2 = fmaf(f1s[e], f1s[e], ps2);
  float ss2 = block_reduce_sum(ps2, rbuf);
  float rinv2 = 1.0f / sqrtf(ss2);
  const float* wrow2 = Wt2 + (size_t)tid * 512;
  float a2 = 0.f;
  for (int c4 = 0; c4 < 128; ++c4) {
    float4 wv = *reinterpret_cast<const float4*>(wrow2 + c4 * 4);
    float4 gv = *reinterpret_cast<const float4*>(&f1s[c4 * 4]);
    a2 = fmaf(wv.x, gv.x, a2); a2 = fmaf(wv.y, gv.y, a2);
    a2 = fmaf(wv.z, gv.z, a2); a2 = fmaf(wv.w, gv.w, a2);
  }
  a2 = a2 * rinv2 + bias2[tid];
  float mean2 = block_reduce_sum(a2, rbuf) * (1.f / 256.f);
  float dd = a2 - mean2;
  float var2 = block_reduce_sum(dd * dd, rbuf) * (1.f / 256.f);
  float rs2 = 1.0f / sqrtf(var2 + 1e-5f);
  f2s[tid] = lrelu((a2 - mean2) * rs2 * g2[tid] + bb2[tid]);
  __syncthreads();
  if (tid < 9) {
    const float* wrow3 = Wt3 + tid * 256;
    float a3 = 0.f;
    for (int c = 0; c < 256; ++c) a3 = fmaf(wrow3[c], f2s[c], a3);
    a3 += bb3[tid];
    if (tid == 0 || tid == 4 || tid == 8) a3 += 1.f;
    tm[tid] = a3;
  }
  __syncthreads();
  const float* xb = x + (size_t)b * 3 * NPTS;
  float* ob = xt + (size_t)b * 3 * NPTS;
  #pragma unroll
  for (int nt = 0; nt < 4; ++nt) {
    const int n = nt * 256 + tid;
    const float x0 = xb[n], x1 = xb[NPTS + n], x2 = xb[2 * NPTS + n];
    #pragma unroll
    for (int i = 0; i < 3; ++i)
      ob[i * NPTS + n] = fmaf(tm[3 * i], x0, fmaf(tm[3 * i + 1], x1, tm[3 * i + 2] * x2));
  }
}

extern "C" void kernel_launch(void* const* d_in, const int* in_sizes, int n_in,
                              void* d_out, int out_size, void* d_ws, size_t ws_size,
                              hipStream_t stream) {
  (void)in_sizes; (void)n_in; (void)out_size; (void)ws_size;
  const float* x       = (const float*)d_in[0];
  const float* tw1     = (const float*)d_in[1];
  const float* tw2     = (const float*)d_in[2];
  const float* tw3     = (const float*)d_in[3];
  const float* tfc1_w  = (const float*)d_in[4];
  const float* tfc1_g  = (const float*)d_in[5];
  const float* tfc1_b  = (const float*)d_in[6];
  const float* tfc2_w  = (const float*)d_in[7];
  const float* tfc2_bias = (const float*)d_in[8];
  const float* tfc2_g  = (const float*)d_in[9];
  const float* tfc2_b  = (const float*)d_in[10];
  const float* tfc3_w  = (const float*)d_in[11];
  const float* tfc3_b  = (const float*)d_in[12];
  const float* w1      = (const float*)d_in[13];
  const float* w2      = (const float*)d_in[14];
  const float* w3      = (const float*)d_in[15];
  const float* w4      = (const float*)d_in[16];
  const float* w5      = (const float*)d_in[17];
  float* out = (float*)d_out;

  char* wsb = (char*)d_ws;
  size_t off = 0;
  auto alloc = [&](size_t bytes) -> void* {
    void* p = wsb + off;
    off += (bytes + 255) & ~(size_t)255;
    return p;
  };
  float* ybuf = (float*)alloc((size_t)BATCH * NPTS * 256 * 4);
  float* zbuf = (float*)alloc((size_t)BATCH * NPTS * 256 * 4);
  float* xcT  = (float*)alloc((size_t)BATCH * 512 * NPTS * 4);   // channel-major fp32 (knn)
  ushort* xc_bf = (ushort*)alloc((size_t)BATCH * NPTS * 512 * 2); // NC bf16 (MFMA)
  float* h2m  = (float*)alloc((size_t)BATCH * 128 * NPTS * 4);
  float* part = (float*)alloc((size_t)BATCH * 16 * 1024 * 4);
  int*   idxb = (int*)alloc((size_t)BATCH * NPTS * KNN * 4);
  float* xxb  = (float*)alloc((size_t)BATCH * NPTS * 4);
  float* xt   = (float*)alloc((size_t)BATCH * 3 * NPTS * 4);
  float* w2aT  = (float*)alloc(64 * 64 * 4);
  float* w2dT  = (float*)alloc(64 * 64 * 4);
  float* w3aT  = (float*)alloc(64 * 128 * 4);
  float* w3dT  = (float*)alloc(64 * 128 * 4);
  ushort* w4a_bf = (ushort*)alloc(256 * 128 * 2);
  ushort* w4d_bf = (ushort*)alloc(256 * 128 * 2);
  ushort* w5_bf  = (ushort*)alloc(1024 * 512 * 2);
  float* tw2T  = (float*)alloc(64 * 128 * 4);
  float* tw3T  = (float*)alloc(128 * 1024 * 4);

  PrepArgs pa;
  pa.w2 = w2; pa.w3 = w3; pa.w4 = w4; pa.w5 = w5; pa.tw2 = tw2; pa.tw3 = tw3;
  pa.w2aT = w2aT; pa.w2dT = w2dT; pa.w3aT = w3aT; pa.w3dT = w3dT;
  pa.w4a_bf = w4a_bf; pa.w4d_bf = w4d_bf; pa.w5_bf = w5_bf;
  pa.tw2T = tw2T; pa.tw3T = tw3T;
  PrepArgs pnone = {};

  // ---- transform net: fused knn<3> + tw1 dual GEMM (inline split) + ALL weight prep ----
  // prep elems = 524288+131072+32768+8192+8192+4096 = 708608 -> 2768 blocks
  knn_dual_kernel<3, 1, 1><<<1024 + 256 + 2768, 256, 0, stream>>>(
      x, 3 * NPTS, nullptr, idxb, tw1, tw1, 64,
      ybuf, zbuf, (long)NPTS * 64, 64, pa);
  h12_gemm_kernel<<<dim3(256, 16), 256, 0, stream>>>(ybuf, zbuf, idxb, tw2T, h2m);
  gemm128_kernel<1><<<dim3(8, 8, 16), 256, 0, stream>>>(h2m, 128 * NPTS, NPTS, tw3T, 1024, 128,
                                                        part, 8 * 1024, 0, 1024);
  fcall_kernel<<<16, 256, 0, stream>>>(part, tfc1_w, tfc1_g, tfc1_b,
                                       tfc2_w, tfc2_bias, tfc2_g, tfc2_b,
                                       tfc3_w, tfc3_b, x, xt);

  // ---- EdgeConv 1: fused knn<3> + w1 dual GEMM (inline split) on xt ----
  knn_dual_kernel<3, 1, 0><<<1280, 256, 0, stream>>>(xt, 3 * NPTS, nullptr, idxb,
                                                     w1, w1, 64,
                                                     ybuf, zbuf, (long)NPTS * 64, 64, pnone);
  edge_max_cn_kernel<64, 64><<<dim3(16, 16), 256, 0, stream>>>(ybuf, zbuf, idxb, xcT, xxb,
                                                               xc_bf, 0);

  // ---- EdgeConv 2: fused knn<64> + w2 dual GEMM on xcT ch0-63 ----
  knn_dual_kernel<64, 1, 0><<<1280, 256, 0, stream>>>(xcT, 512 * NPTS, xxb, idxb,
                                                      w2aT, w2dT, 64,
                                                      ybuf, zbuf, (long)NPTS * 64, 64, pnone);
  edge_max_cn_kernel<64, 64><<<dim3(16, 16), 256, 0, stream>>>(ybuf, zbuf, idxb,
                                                               xcT + 64 * NPTS, xxb, xc_bf, 64);

  // ---- EdgeConv 3: fused knn<64> + w3 dual GEMM on xcT ch64-127 ----
  knn_dual_kernel<64, 2, 0><<<1536, 256, 0, stream>>>(xcT + 64 * NPTS, 512 * NPTS, xxb, idxb,
                                                      w3aT, w3dT, 128,
                                                      ybuf, zbuf, (long)NPTS * 128, 128, pnone);
  edge_max_cn_kernel<128, 64><<<dim3(16, 16), 256, 0, stream>>>(ybuf, zbuf, idxb,
                                                                xcT + 128 * NPTS, xxb, xc_bf, 128);

  // ---- EdgeConv 4: fused knn<128> + both w4 bf16 MFMA GEMMs ----
  knn_mfma_kernel<<<1536, 256, 0, stream>>>(xcT + 128 * NPTS, 512 * NPTS, xxb, idxb,
                                            xc_bf + 128, w4a_bf, w4d_bf, ybuf, zbuf);
  edge_max_cn_kernel<256, 32><<<dim3(32, 16), 256, 0, stream>>>(ybuf, zbuf, idxb,
                                                                xcT + 256 * NPTS, nullptr,
                                                                xc_bf, 256);

  // ---- final: x5 = lrelu(w5 @ xc) with max over n — bf16 MFMA ----
  gemm_mfma_kernel<1><<<dim3(8, 8, 16), 256, 0, stream>>>(xc_bf, (long)NPTS * 512, 512,
                                                          w5_bf, 512, 512,
                                                          part, 8 * 1024, 0, 1024);
  reduce_max_kernel<<<dim3(4, 16), 256, 0, stream>>>(part, out, 8);
}